// Round 9
// baseline (78.216 us; speedup 1.0000x reference)
//
#include <hip/hip_runtime.h>
#include <hip/hip_bf16.h>
#include <math.h>

#define BB 8
#define TT 2048
#define DD 512
#define NT2 8   // 256-col tiles per batch row

typedef __attribute__((ext_vector_type(8))) short bf16x8;
typedef __attribute__((ext_vector_type(4))) float f32x4;

__device__ inline float softplus_f(float v) { return log1pf(expf(v)); }

// fast tanh: 1 - 2/(exp2(2*log2e*y)+1); v_exp_f32 + v_rcp_f32, ~1e-6 rel err
__device__ inline float tanh_fast(float y) {
    float e = __builtin_amdgcn_exp2f(y * 2.8853900817779268f);
    return 1.0f - 2.0f * __builtin_amdgcn_rcpf(e + 1.0f);
}
__device__ inline float exp_fast(float y) {
    return __builtin_amdgcn_exp2f(y * 1.4426950408889634f);
}

// f32 -> bf16 via compiler cast (emits v_cvt_pk_bf16_f32 pairs; m240)
__device__ inline unsigned short cvt_bf16(float f) {
    __hip_bfloat16 h = (__hip_bfloat16)f;
    return *reinterpret_cast<unsigned short*>(&h);
}
__device__ inline float bf2f(unsigned short h) {
    unsigned int u = ((unsigned int)h) << 16;
    return __uint_as_float(u);
}

__device__ inline void load_lds16(const void* g, void* l) {
    __builtin_amdgcn_global_load_lds(
        (const __attribute__((address_space(1))) unsigned int*)g,
        (__attribute__((address_space(3))) unsigned int*)l, 16, 0, 0);
}

// ---------------- K1: fused prep + per-row elementwise + reductions ----------------
// 256 threads = 4 waves; one wave per row of D=512; 8 elems/thread.
// Writes XN (normalized x, bf16) and PO (gelu*gate_hist*gate_cos, bf16).
__global__ __launch_bounds__(256) void k1_elem(
    const float* __restrict__ x, const float* __restrict__ ema_mean,
    const float* __restrict__ ema_sq, const float* __restrict__ ema_out,
    const float* __restrict__ p_log_tau, const float* __restrict__ p_lbu,
    const float* __restrict__ p_lbd, const float* __restrict__ p_lg,
    unsigned short* __restrict__ xn, unsigned short* __restrict__ po) {
    const int row = blockIdx.x * 4 + (threadIdx.x >> 6);
    const int lane = threadIdx.x & 63;
    const size_t base = (size_t)row * DD;

    const float tau = expf(p_log_tau[0]);
    const float beta_up = softplus_f(p_lbu[0]);
    const float beta_dn = softplus_f(p_lbd[0]);
    const float gamma = softplus_f(p_lg[0]);

    float xv[8], pg[8];
    float sx2 = 0.f, so2 = 0.f, sod = 0.f, se2 = 0.f;
#pragma unroll
    for (int c = 0; c < 2; ++c) {
        const int j0 = c * 256 + lane * 4;
        float4 xx = *reinterpret_cast<const float4*>(x + base + j0);
        float4 mm = *reinterpret_cast<const float4*>(ema_mean + j0);
        float4 qq = *reinterpret_cast<const float4*>(ema_sq + j0);
        float4 eo = *reinterpret_cast<const float4*>(ema_out + j0);
        float vv[4] = {xx.x, xx.y, xx.z, xx.w};
        float vm[4] = {mm.x, mm.y, mm.z, mm.w};
        float vq[4] = {qq.x, qq.y, qq.z, qq.w};
        float ve[4] = {eo.x, eo.y, eo.z, eo.w};
#pragma unroll
        for (int q = 0; q < 4; ++q) {
            const int e = c * 4 + q;
            float xf = vv[q];
            xv[e] = xf;
            // gelu (tanh approx)
            float x3 = xf * xf * xf;
            float gl = 0.5f * xf * (1.0f + tanh_fast(0.7978845608028654f * (xf + 0.044715f * x3)));
            // z-gate (inv_std inline)
            float var = fmaxf(vq[q] - vm[q] * vm[q], 1e-4f);
            float istd = __builtin_amdgcn_rcpf(sqrtf(var) + 1e-5f);
            float z = (xf - vm[q]) * istd;
            float th = tanh_fast(gamma * z);
            float up = beta_up * fmaxf(th, 0.0f);
            float dn = beta_dn * fmaxf(-th, 0.0f);
            float gh = fminf(fmaxf(1.0f + up - dn, 0.05f), 8.0f);
            pg[e] = gl * gh;
            sx2 += xf * xf;
            so2 += gl * gl;
            sod += gl * ve[q];
            se2 += ve[q] * ve[q];
        }
    }
#pragma unroll
    for (int off = 32; off; off >>= 1) {
        sx2 += __shfl_xor(sx2, off);
        so2 += __shfl_xor(so2, off);
        sod += __shfl_xor(sod, off);
        se2 += __shfl_xor(se2, off);
    }
    const float inv_xnorm = __builtin_amdgcn_rcpf(fmaxf(sqrtf(sx2), 1e-12f));
    const float inv_en = __builtin_amdgcn_rcpf(fmaxf(sqrtf(se2), 1e-12f));
    float cosv = sod * inv_en * __builtin_amdgcn_rcpf(fmaxf(sqrtf(so2), 1e-12f));
    cosv = fminf(fmaxf(cosv, -1.0f), 1.0f);
    const float gcos = exp_fast(-tau * cosv);

#pragma unroll
    for (int c = 0; c < 2; ++c) {
        const int j0 = c * 256 + lane * 4;
        ushort4 pb;
        pb.x = cvt_bf16(pg[c * 4 + 0] * gcos);
        pb.y = cvt_bf16(pg[c * 4 + 1] * gcos);
        pb.z = cvt_bf16(pg[c * 4 + 2] * gcos);
        pb.w = cvt_bf16(pg[c * 4 + 3] * gcos);
        *reinterpret_cast<ushort4*>(po + base + j0) = pb;
        ushort4 xb;
        xb.x = cvt_bf16(xv[c * 4 + 0] * inv_xnorm);
        xb.y = cvt_bf16(xv[c * 4 + 1] * inv_xnorm);
        xb.z = cvt_bf16(xv[c * 4 + 2] * inv_xnorm);
        xb.w = cvt_bf16(xv[c * 4 + 3] * inv_xnorm);
        *reinterpret_cast<ushort4*>(xn + base + j0) = xb;
    }
}

// ---------------- K2: sim row-max via MFMA, 256x256 tile, counted-vmcnt pipeline ----
// 512 threads = 8 waves (2 row-halves x 4 col-quarters), per-wave 128x64 out.
// BK=32, FOUR LDS slots (32 KB each): stage runs 3 K-tiles ahead; boundary
// s_waitcnt vmcnt(8) + raw s_barrier (collectively: tile t complete, newest 2
// tiles in flight, T4). NEW (R8->R9): inline-asm ds_read_b128 in fixed order
// (bv0-3, av0-7) + per-MFMA-group s_waitcnt lgkmcnt(7-mi) + sched_barrier(0)
// (rule 18) so groups mi+1..7's reads drain UNDER group mi's MFMAs — R8's
// counters showed the read phase and MFMA phase fully serialized (33% util,
// both ~1200 cyc/tile/CU).
// LDS packing: 2 logical 64B rows per 128B LDS row, XOR-swizzle (2-way = free,
// PMC-verified 0 conflicts); gload_lds dest linear, global source
// inverse-swizzled (rule 21). Full matrix; XCD pin b = bid&7.
__global__ __launch_bounds__(512, 2) void k2_nn(const unsigned short* __restrict__ xn,
                                                float* __restrict__ partial) {
    __shared__ char lds[131072];  // 4 slots x (A 16KB | B 16KB); base offset 0

    const int tid = threadIdx.x;
    const int wave = tid >> 6;
    const int lane = tid & 63;
    const int r15 = lane & 15;
    const int kgrp = lane >> 4;
    const int wr = wave >> 2;  // 0..1 (row half)
    const int wc = wave & 3;   // 0..3 (col quarter)

    const int bid = blockIdx.x;
    const int b = bid & 7;       // XCD pin
    const int t0 = bid >> 3;     // 0..63
    const int tm = t0 >> 3, tn = t0 & 7;

    const size_t bbase = (size_t)b * TT * DD;
    const unsigned short* Ag = xn + bbase + (size_t)tm * 256 * DD;
    const unsigned short* Bg = xn + bbase + (size_t)tn * 256 * DD;

    f32x4 acc[8][4];
#pragma unroll
    for (int i = 0; i < 8; ++i)
#pragma unroll
        for (int j = 0; j < 4; ++j) acc[i][j] = (f32x4){0.f, 0.f, 0.f, 0.f};

    // ---- stage: 4 gload_lds per thread per K-tile (A:2 + B:2) ----
    auto stage = [&](int slot, int kt) {
#pragma unroll
        for (int c = 0; c < 2; ++c) {
            const int o = c * 8192 + tid * 16;
            const int sup = o >> 7;
            const int w = (o & 127) ^ ((sup & 7) << 4);
            const int row = sup * 2 + (w >> 6);
            const int ce = (w & 63) >> 1;
            const size_t gof = (size_t)row * DD + kt * 32 + ce;
            load_lds16(Ag + gof, lds + slot * 32768 + o);
            load_lds16(Bg + gof, lds + slot * 32768 + 16384 + o);
        }
    };

    // fragment byte offset for logical row R, col-block kgrp (16B)
#define LADDR(R) \
    (((R) >> 1) * 128 + (((((R) & 1) << 6) + (kgrp << 4)) ^ ((((R) >> 1) & 7) << 4)))

    unsigned offB[4], offA[8];
#pragma unroll
    for (int ni = 0; ni < 4; ++ni) {
        const int R = wc * 64 + ni * 16 + r15;
        offB[ni] = 16384u + (unsigned)LADDR(R);
    }
#pragma unroll
    for (int mi = 0; mi < 8; ++mi) {
        const int R = wr * 128 + mi * 16 + r15;
        offA[mi] = (unsigned)LADDR(R);
    }
#undef LADDR

#define RD(DST, OFF) \
    asm volatile("ds_read_b128 %0, %1" : "=v"(DST) : "v"(OFF))

#define GRP(MI, AV, N)                                                        \
    asm volatile("s_waitcnt lgkmcnt(" #N ")" ::: "memory");                   \
    __builtin_amdgcn_sched_barrier(0);                                        \
    acc[MI][0] = __builtin_amdgcn_mfma_f32_16x16x32_bf16(AV, bv0, acc[MI][0], 0, 0, 0); \
    acc[MI][1] = __builtin_amdgcn_mfma_f32_16x16x32_bf16(AV, bv1, acc[MI][1], 0, 0, 0); \
    acc[MI][2] = __builtin_amdgcn_mfma_f32_16x16x32_bf16(AV, bv2, acc[MI][2], 0, 0, 0); \
    acc[MI][3] = __builtin_amdgcn_mfma_f32_16x16x32_bf16(AV, bv3, acc[MI][3], 0, 0, 0)

#define COMPUTE(SLOT)                                                         \
    do {                                                                      \
        const unsigned sb = (unsigned)(SLOT) * 32768u;                        \
        bf16x8 bv0, bv1, bv2, bv3, av0, av1, av2, av3, av4, av5, av6, av7;    \
        RD(bv0, offB[0] + sb); RD(bv1, offB[1] + sb);                         \
        RD(bv2, offB[2] + sb); RD(bv3, offB[3] + sb);                         \
        RD(av0, offA[0] + sb); RD(av1, offA[1] + sb);                         \
        RD(av2, offA[2] + sb); RD(av3, offA[3] + sb);                         \
        RD(av4, offA[4] + sb); RD(av5, offA[5] + sb);                         \
        RD(av6, offA[6] + sb); RD(av7, offA[7] + sb);                         \
        __builtin_amdgcn_s_setprio(1);                                        \
        GRP(0, av0, 7); GRP(1, av1, 6); GRP(2, av2, 5); GRP(3, av3, 4);       \
        GRP(4, av4, 3); GRP(5, av5, 2); GRP(6, av6, 1); GRP(7, av7, 0);       \
        __builtin_amdgcn_s_setprio(0);                                        \
    } while (0)

    // prologue: stage tiles 0,1,2 (12 loads/thread); collective wait: tile 0
    // complete after all waves pass vmcnt(8)+barrier (8 = tiles 1,2 in flight)
    stage(0, 0);
    stage(1, 1);
    stage(2, 2);
    asm volatile("s_waitcnt vmcnt(8)" ::: "memory");
    __builtin_amdgcn_s_barrier();
    __builtin_amdgcn_sched_barrier(0);

#pragma unroll
    for (int t = 0; t < 16; ++t) {
        if (t + 3 < 16) stage((t + 3) & 3, t + 3);  // slot (t-1)&3: reads done last iter
        COMPUTE(t & 3);
        if (t < 15) {
            if (t <= 12)
                asm volatile("s_waitcnt vmcnt(8)" ::: "memory");
            else if (t == 13)
                asm volatile("s_waitcnt vmcnt(4)" ::: "memory");
            else
                asm volatile("s_waitcnt vmcnt(0)" ::: "memory");
            __builtin_amdgcn_s_barrier();
            __builtin_amdgcn_sched_barrier(0);
        }
    }
#undef COMPUTE
#undef GRP
#undef RD

    // ---- epilogue: row-max (fold ni + 16-lane shfl), diagonal masked ----
    // D layout: col = wc*64 + ni*16 + r15, row = wr*128 + mi*16 + kgrp*4 + r
    const bool diag = (tm == tn);
    float rmx[8][4];
#pragma unroll
    for (int mi = 0; mi < 8; ++mi) {
#pragma unroll
        for (int r = 0; r < 4; ++r) {
            const int rl = wr * 128 + mi * 16 + kgrp * 4 + r;
            float v = -2.0f;
#pragma unroll
            for (int ni = 0; ni < 4; ++ni) {
                float e = acc[mi][ni][r];
                if (diag && (wc * 64 + ni * 16 + r15) == rl) e = -2.0f;
                v = fmaxf(v, e);
            }
            v = fmaxf(v, __shfl_xor(v, 1));
            v = fmaxf(v, __shfl_xor(v, 2));
            v = fmaxf(v, __shfl_xor(v, 4));
            v = fmaxf(v, __shfl_xor(v, 8));
            rmx[mi][r] = v;
        }
    }
    __syncthreads();  // all LDS tile reads done; safe to alias rbuf onto lds
    float* rbuf = (float*)lds;  // [256 rows][4 wc]
    if (r15 == 0) {
#pragma unroll
        for (int mi = 0; mi < 8; ++mi)
#pragma unroll
            for (int r = 0; r < 4; ++r)
                rbuf[(wr * 128 + mi * 16 + kgrp * 4 + r) * 4 + wc] = rmx[mi][r];
    }
    __syncthreads();
    if (tid < 256) {
        const float v = fmaxf(fmaxf(rbuf[tid * 4 + 0], rbuf[tid * 4 + 1]),
                              fmaxf(rbuf[tid * 4 + 2], rbuf[tid * 4 + 3]));
        partial[((size_t)b * TT + tm * 256 + tid) * NT2 + tn] = v;
    }
}

// ---------------- K3: reduce partial maxes + gate_nn scale + final write ----------------
// 256 threads = 4 waves; one wave per row; reads bf16 PO, writes f32 out.
__global__ __launch_bounds__(256) void k3_scale(float* __restrict__ out,
                                                const unsigned short* __restrict__ po,
                                                const float* __restrict__ partial,
                                                const float* __restrict__ p_lsn,
                                                const float* __restrict__ p_lwn) {
    const int row = blockIdx.x * 4 + (threadIdx.x >> 6);
    const int lane = threadIdx.x & 63;
    const float sigma_nn = softplus_f(p_lsn[0]);
    const float w_nn = softplus_f(p_lwn[0]);

    float p = partial[(size_t)row * NT2 + (lane & 7)];
    p = fmaxf(p, __shfl_xor(p, 1));
    p = fmaxf(p, __shfl_xor(p, 2));
    p = fmaxf(p, __shfl_xor(p, 4));
    const float g = 1.0f + w_nn * tanh_fast(sigma_nn * 0.5f * (1.0f - p));

    const size_t base = (size_t)row * DD + lane * 8;
    ushort4 p0 = *reinterpret_cast<const ushort4*>(po + base);
    ushort4 p1 = *reinterpret_cast<const ushort4*>(po + base + 4);
    float4 o0, o1;
    o0.x = bf2f(p0.x) * g; o0.y = bf2f(p0.y) * g;
    o0.z = bf2f(p0.z) * g; o0.w = bf2f(p0.w) * g;
    o1.x = bf2f(p1.x) * g; o1.y = bf2f(p1.y) * g;
    o1.z = bf2f(p1.z) * g; o1.w = bf2f(p1.w) * g;
    *reinterpret_cast<float4*>(out + base) = o0;
    *reinterpret_cast<float4*>(out + base + 4) = o1;
}

extern "C" void kernel_launch(void* const* d_in, const int* in_sizes, int n_in,
                              void* d_out, int out_size, void* d_ws, size_t ws_size,
                              hipStream_t stream) {
    const float* x = (const float*)d_in[0];
    const float* ema_mean = (const float*)d_in[1];
    const float* ema_sq = (const float*)d_in[2];
    const float* ema_out = (const float*)d_in[3];
    const float* log_tau = (const float*)d_in[4];
    const float* log_beta_up = (const float*)d_in[5];
    const float* log_beta_dn = (const float*)d_in[6];
    const float* log_gamma = (const float*)d_in[7];
    const float* log_sigma_nn = (const float*)d_in[8];
    const float* log_w_nn = (const float*)d_in[9];

    // ws layout: XN bf16 [B*T*D] (16.78 MB) | PO bf16 [B*T*D] (16.78 MB)
    //            | partial f32[B*T][NT2] (512 KB)
    char* ws = (char*)d_ws;
    unsigned short* XN = (unsigned short*)ws;
    unsigned short* PO = (unsigned short*)(ws + 16777216);
    float* partial = (float*)(ws + 33554432);
    float* out = (float*)d_out;

    hipLaunchKernelGGL(k1_elem, dim3(BB * TT / 4), dim3(256), 0, stream, x, ema_mean, ema_sq,
                       ema_out, log_tau, log_beta_up, log_beta_dn, log_gamma, XN, PO);
    hipLaunchKernelGGL(k2_nn, dim3(BB * 64), dim3(512), 0, stream, XN, partial);
    hipLaunchKernelGGL(k3_scale, dim3(BB * TT / 4), dim3(256), 0, stream, out, PO, partial,
                       log_sigma_nn, log_w_nn);
}

// Round 10
// 78.056 us; speedup vs baseline: 1.0021x; 1.0021x over previous
//
#include <hip/hip_runtime.h>
#include <hip/hip_bf16.h>
#include <math.h>

#define BB 8
#define TT 2048
#define DD 512
#define NT2 8   // 256-col tiles per batch row

typedef __attribute__((ext_vector_type(8))) short bf16x8;
typedef __attribute__((ext_vector_type(4))) float f32x4;

__device__ inline float softplus_f(float v) { return log1pf(expf(v)); }

// fast tanh: 1 - 2/(exp2(2*log2e*y)+1); v_exp_f32 + v_rcp_f32, ~1e-6 rel err
__device__ inline float tanh_fast(float y) {
    float e = __builtin_amdgcn_exp2f(y * 2.8853900817779268f);
    return 1.0f - 2.0f * __builtin_amdgcn_rcpf(e + 1.0f);
}
__device__ inline float exp_fast(float y) {
    return __builtin_amdgcn_exp2f(y * 1.4426950408889634f);
}

// f32 -> bf16 via compiler cast (emits v_cvt_pk_bf16_f32 pairs; m240)
__device__ inline unsigned short cvt_bf16(float f) {
    __hip_bfloat16 h = (__hip_bfloat16)f;
    return *reinterpret_cast<unsigned short*>(&h);
}
__device__ inline float bf2f(unsigned short h) {
    unsigned int u = ((unsigned int)h) << 16;
    return __uint_as_float(u);
}

__device__ inline void load_lds16(const void* g, void* l) {
    __builtin_amdgcn_global_load_lds(
        (const __attribute__((address_space(1))) unsigned int*)g,
        (__attribute__((address_space(3))) unsigned int*)l, 16, 0, 0);
}

// ---------------- K0: per-channel prep (inv_std, normalized ema_out) ----------------
__global__ __launch_bounds__(512) void k0_prep(const float* __restrict__ ema_mean,
                                               const float* __restrict__ ema_sq,
                                               const float* __restrict__ ema_out,
                                               float* __restrict__ inv_std,
                                               float* __restrict__ ema_n) {
    __shared__ float red[8];
    int t = threadIdx.x;  // 512 threads, one per channel
    float m = ema_mean[t];
    float v = ema_sq[t] - m * m;
    v = fmaxf(v, 1e-4f);
    inv_std[t] = 1.0f / (sqrtf(v) + 1e-5f);

    float e = ema_out[t];
    float s = e * e;
#pragma unroll
    for (int off = 32; off; off >>= 1) s += __shfl_xor(s, off);
    if ((t & 63) == 0) red[t >> 6] = s;
    __syncthreads();
    if (t == 0) {
        float tot = 0.f;
        for (int i = 0; i < 8; ++i) tot += red[i];
        red[0] = 1.0f / fmaxf(sqrtf(tot), 1e-12f);
    }
    __syncthreads();
    ema_n[t] = e * red[0];
}

// ---------------- K1: per-row elementwise + reductions ----------------
// 256 threads = 4 waves; one wave per row of D=512; 8 elems/thread.
// inv_std / ema_n precomputed by k0 (removes per-elem sqrt+rcp trans ops).
__global__ __launch_bounds__(256) void k1_elem(
    const float* __restrict__ x, const float* __restrict__ ema_mean,
    const float* __restrict__ inv_std, const float* __restrict__ ema_n,
    const float* __restrict__ p_log_tau, const float* __restrict__ p_lbu,
    const float* __restrict__ p_lbd, const float* __restrict__ p_lg,
    unsigned short* __restrict__ xn, unsigned short* __restrict__ po) {
    const int row = blockIdx.x * 4 + (threadIdx.x >> 6);
    const int lane = threadIdx.x & 63;
    const size_t base = (size_t)row * DD;

    const float tau = expf(p_log_tau[0]);
    const float beta_up = softplus_f(p_lbu[0]);
    const float beta_dn = softplus_f(p_lbd[0]);
    const float gamma = softplus_f(p_lg[0]);

    float xv[8], pg[8];
    float sx2 = 0.f, so2 = 0.f, sod = 0.f;
#pragma unroll
    for (int c = 0; c < 2; ++c) {
        const int j0 = c * 256 + lane * 4;
        float4 xx = *reinterpret_cast<const float4*>(x + base + j0);
        float4 mm = *reinterpret_cast<const float4*>(ema_mean + j0);
        float4 ii = *reinterpret_cast<const float4*>(inv_std + j0);
        float4 eo = *reinterpret_cast<const float4*>(ema_n + j0);
        float vv[4] = {xx.x, xx.y, xx.z, xx.w};
        float vm[4] = {mm.x, mm.y, mm.z, mm.w};
        float vi[4] = {ii.x, ii.y, ii.z, ii.w};
        float ve[4] = {eo.x, eo.y, eo.z, eo.w};
#pragma unroll
        for (int q = 0; q < 4; ++q) {
            const int e = c * 4 + q;
            float xf = vv[q];
            xv[e] = xf;
            // gelu (tanh approx)
            float x3 = xf * xf * xf;
            float gl = 0.5f * xf * (1.0f + tanh_fast(0.7978845608028654f * (xf + 0.044715f * x3)));
            // z-gate
            float z = (xf - vm[q]) * vi[q];
            float th = tanh_fast(gamma * z);
            float up = beta_up * fmaxf(th, 0.0f);
            float dn = beta_dn * fmaxf(-th, 0.0f);
            float gh = fminf(fmaxf(1.0f + up - dn, 0.05f), 8.0f);
            pg[e] = gl * gh;
            sx2 += xf * xf;
            so2 += gl * gl;
            sod += gl * ve[q];
        }
    }
#pragma unroll
    for (int off = 32; off; off >>= 1) {
        sx2 += __shfl_xor(sx2, off);
        so2 += __shfl_xor(so2, off);
        sod += __shfl_xor(sod, off);
    }
    const float inv_xnorm = __builtin_amdgcn_rcpf(fmaxf(sqrtf(sx2), 1e-12f));
    float cosv = sod * __builtin_amdgcn_rcpf(fmaxf(sqrtf(so2), 1e-12f));
    cosv = fminf(fmaxf(cosv, -1.0f), 1.0f);
    const float gcos = exp_fast(-tau * cosv);

#pragma unroll
    for (int c = 0; c < 2; ++c) {
        const int j0 = c * 256 + lane * 4;
        ushort4 pb;
        pb.x = cvt_bf16(pg[c * 4 + 0] * gcos);
        pb.y = cvt_bf16(pg[c * 4 + 1] * gcos);
        pb.z = cvt_bf16(pg[c * 4 + 2] * gcos);
        pb.w = cvt_bf16(pg[c * 4 + 3] * gcos);
        *reinterpret_cast<ushort4*>(po + base + j0) = pb;
        ushort4 xb;
        xb.x = cvt_bf16(xv[c * 4 + 0] * inv_xnorm);
        xb.y = cvt_bf16(xv[c * 4 + 1] * inv_xnorm);
        xb.z = cvt_bf16(xv[c * 4 + 2] * inv_xnorm);
        xb.w = cvt_bf16(xv[c * 4 + 3] * inv_xnorm);
        *reinterpret_cast<ushort4*>(xn + base + j0) = xb;
    }
}

// ---------------- K2: sim row-max, 256x256 tile, cross-tile register prefetch ----
// 512 threads = 8 waves (2x4), per-wave 128x64 out, BK=32, 4 LDS slots (128 KB).
// R9's failure: barrier-locked waves convoy (all read, then all MFMA — phases
// serialize). Fix: REGISTER prefetch across tiles — per iter: stage(t+3);
// issue ds_reads for curA4..7 (tile t) AND nxt {B0..3,A0..3} (tile t+1);
// lgkmcnt(12) -> tile t's prefetched set (read LAST iter) is ready with zero
// wait; GRP0-3 MFMAs run while the 12 fresh reads drain; lgkmcnt(8) -> A4..7
// ready; GRP4-7. Boundary: vmcnt(4) (tile t+2 landed collectively after
// barrier; tile t+3 stays in flight) + raw s_barrier + sched_barrier (T4).
// Dual-buffered prefetch = 64 VGPR, A47 16, acc 128 -> ~240 total, keeps
// 2 waves/SIMD. LDS layout/swizzle identical to R8/R9 (PMC: 0 conflicts).
__global__ __launch_bounds__(512, 2) void k2_nn(const unsigned short* __restrict__ xn,
                                                float* __restrict__ partial) {
    __shared__ char lds[131072];  // 4 slots x (A 16KB | B 16KB)

    const int tid = threadIdx.x;
    const int wave = tid >> 6;
    const int lane = tid & 63;
    const int r15 = lane & 15;
    const int kgrp = lane >> 4;
    const int wr = wave >> 2;  // 0..1 (row half)
    const int wc = wave & 3;   // 0..3 (col quarter)

    const int bid = blockIdx.x;
    const int b = bid & 7;       // XCD pin
    const int t0 = bid >> 3;     // 0..63
    const int tm = t0 >> 3, tn = t0 & 7;

    const size_t bbase = (size_t)b * TT * DD;
    const unsigned short* Ag = xn + bbase + (size_t)tm * 256 * DD;
    const unsigned short* Bg = xn + bbase + (size_t)tn * 256 * DD;

    f32x4 acc[8][4];
#pragma unroll
    for (int i = 0; i < 8; ++i)
#pragma unroll
        for (int j = 0; j < 4; ++j) acc[i][j] = (f32x4){0.f, 0.f, 0.f, 0.f};

    // ---- stage: 4 gload_lds per thread per K-tile (A:2 + B:2) ----
    auto stage = [&](int slot, int kt) {
#pragma unroll
        for (int c = 0; c < 2; ++c) {
            const int o = c * 8192 + tid * 16;
            const int sup = o >> 7;
            const int w = (o & 127) ^ ((sup & 7) << 4);
            const int row = sup * 2 + (w >> 6);
            const int ce = (w & 63) >> 1;
            const size_t gof = (size_t)row * DD + kt * 32 + ce;
            load_lds16(Ag + gof, lds + slot * 32768 + o);
            load_lds16(Bg + gof, lds + slot * 32768 + 16384 + o);
        }
    };

    // fragment byte offset for logical row R, col-block kgrp (16B).
    // LADDR(R+16) = LADDR(R) + 1024 -> per-fragment offsets are immediates.
#define LADDR(R) \
    (((R) >> 1) * 128 + (((((R) & 1) << 6) + (kgrp << 4)) ^ ((((R) >> 1) & 7) << 4)))
    const unsigned offA0 = (unsigned)LADDR(wr * 128 + r15);
    const unsigned offB0 = 16384u + (unsigned)LADDR(wc * 64 + r15);
#undef LADDR

    bf16x8 PB[2][4], PA[2][4], A47[4];

#define RDA47(ADDR)                                                                     \
    asm volatile("ds_read_b128 %0, %1 offset:4096" : "=v"(A47[0]) : "v"(ADDR));         \
    asm volatile("ds_read_b128 %0, %1 offset:5120" : "=v"(A47[1]) : "v"(ADDR));         \
    asm volatile("ds_read_b128 %0, %1 offset:6144" : "=v"(A47[2]) : "v"(ADDR));         \
    asm volatile("ds_read_b128 %0, %1 offset:7168" : "=v"(A47[3]) : "v"(ADDR))
#define RDPB(S, ADDR)                                                                   \
    asm volatile("ds_read_b128 %0, %1" : "=v"(PB[S][0]) : "v"(ADDR));                   \
    asm volatile("ds_read_b128 %0, %1 offset:1024" : "=v"(PB[S][1]) : "v"(ADDR));       \
    asm volatile("ds_read_b128 %0, %1 offset:2048" : "=v"(PB[S][2]) : "v"(ADDR));       \
    asm volatile("ds_read_b128 %0, %1 offset:3072" : "=v"(PB[S][3]) : "v"(ADDR))
#define RDPA(S, ADDR)                                                                   \
    asm volatile("ds_read_b128 %0, %1" : "=v"(PA[S][0]) : "v"(ADDR));                   \
    asm volatile("ds_read_b128 %0, %1 offset:1024" : "=v"(PA[S][1]) : "v"(ADDR));       \
    asm volatile("ds_read_b128 %0, %1 offset:2048" : "=v"(PA[S][2]) : "v"(ADDR));       \
    asm volatile("ds_read_b128 %0, %1 offset:3072" : "=v"(PA[S][3]) : "v"(ADDR))

#define GRPQ(S, MI)                                                                     \
    acc[MI][0] = __builtin_amdgcn_mfma_f32_16x16x32_bf16(PA[S][MI], PB[S][0], acc[MI][0], 0, 0, 0); \
    acc[MI][1] = __builtin_amdgcn_mfma_f32_16x16x32_bf16(PA[S][MI], PB[S][1], acc[MI][1], 0, 0, 0); \
    acc[MI][2] = __builtin_amdgcn_mfma_f32_16x16x32_bf16(PA[S][MI], PB[S][2], acc[MI][2], 0, 0, 0); \
    acc[MI][3] = __builtin_amdgcn_mfma_f32_16x16x32_bf16(PA[S][MI], PB[S][3], acc[MI][3], 0, 0, 0)
#define GRPH(S, Q)                                                                      \
    acc[4 + Q][0] = __builtin_amdgcn_mfma_f32_16x16x32_bf16(A47[Q], PB[S][0], acc[4 + Q][0], 0, 0, 0); \
    acc[4 + Q][1] = __builtin_amdgcn_mfma_f32_16x16x32_bf16(A47[Q], PB[S][1], acc[4 + Q][1], 0, 0, 0); \
    acc[4 + Q][2] = __builtin_amdgcn_mfma_f32_16x16x32_bf16(A47[Q], PB[S][2], acc[4 + Q][2], 0, 0, 0); \
    acc[4 + Q][3] = __builtin_amdgcn_mfma_f32_16x16x32_bf16(A47[Q], PB[S][3], acc[4 + Q][3], 0, 0, 0)

    // prologue: stage tiles 0,1,2; vmcnt(4) -> tiles 0,1 landed; barrier;
    // prefetch tile0's {B,A0..3} into set 0.
    stage(0, 0);
    stage(1, 1);
    stage(2, 2);
    asm volatile("s_waitcnt vmcnt(4)" ::: "memory");
    __builtin_amdgcn_s_barrier();
    __builtin_amdgcn_sched_barrier(0);
    {
        unsigned aB = offB0, aA = offA0;
        RDPB(0, aB);
        RDPA(0, aA);
    }

#pragma unroll
    for (int t = 0; t < 16; ++t) {
        if (t <= 12) stage((t + 3) & 3, t + 3);
        const unsigned sbC = (unsigned)((t & 3) * 32768);
        const unsigned sbN = (unsigned)(((t + 1) & 3) * 32768);
        unsigned aC = offA0 + sbC;
        RDA47(aC);
        if (t < 15) {
            unsigned aBn = offB0 + sbN;
            unsigned aAn = offA0 + sbN;
            if ((t & 1) == 0) { RDPB(1, aBn); RDPA(1, aAn); }
            else              { RDPB(0, aBn); RDPA(0, aAn); }
            asm volatile("s_waitcnt lgkmcnt(12)" ::: "memory");
        } else {
            asm volatile("s_waitcnt lgkmcnt(4)" ::: "memory");
        }
        __builtin_amdgcn_sched_barrier(0);
        __builtin_amdgcn_s_setprio(1);
        if ((t & 1) == 0) { GRPQ(0, 0); GRPQ(0, 1); GRPQ(0, 2); GRPQ(0, 3); }
        else              { GRPQ(1, 0); GRPQ(1, 1); GRPQ(1, 2); GRPQ(1, 3); }
        __builtin_amdgcn_s_setprio(0);
        if (t < 15) asm volatile("s_waitcnt lgkmcnt(8)" ::: "memory");
        else        asm volatile("s_waitcnt lgkmcnt(0)" ::: "memory");
        __builtin_amdgcn_sched_barrier(0);
        __builtin_amdgcn_s_setprio(1);
        if ((t & 1) == 0) { GRPH(0, 0); GRPH(0, 1); GRPH(0, 2); GRPH(0, 3); }
        else              { GRPH(1, 0); GRPH(1, 1); GRPH(1, 2); GRPH(1, 3); }
        __builtin_amdgcn_s_setprio(0);
        if (t <= 12)
            asm volatile("s_waitcnt vmcnt(4)" ::: "memory");
        else if (t <= 14)
            asm volatile("s_waitcnt vmcnt(0)" ::: "memory");
        if (t < 15) {
            __builtin_amdgcn_s_barrier();
            __builtin_amdgcn_sched_barrier(0);
        }
    }
#undef RDA47
#undef RDPB
#undef RDPA
#undef GRPQ
#undef GRPH

    // ---- epilogue: row-max (fold ni + 16-lane shfl), diagonal masked ----
    // D layout: col = wc*64 + ni*16 + r15, row = wr*128 + mi*16 + kgrp*4 + r
    const bool diag = (tm == tn);
    float rmx[8][4];
#pragma unroll
    for (int mi = 0; mi < 8; ++mi) {
#pragma unroll
        for (int r = 0; r < 4; ++r) {
            const int rl = wr * 128 + mi * 16 + kgrp * 4 + r;
            float v = -2.0f;
#pragma unroll
            for (int ni = 0; ni < 4; ++ni) {
                float e = acc[mi][ni][r];
                if (diag && (wc * 64 + ni * 16 + r15) == rl) e = -2.0f;
                v = fmaxf(v, e);
            }
            v = fmaxf(v, __shfl_xor(v, 1));
            v = fmaxf(v, __shfl_xor(v, 2));
            v = fmaxf(v, __shfl_xor(v, 4));
            v = fmaxf(v, __shfl_xor(v, 8));
            rmx[mi][r] = v;
        }
    }
    __syncthreads();  // all LDS tile reads done; safe to alias rbuf onto lds
    float* rbuf = (float*)lds;  // [256 rows][4 wc]
    if (r15 == 0) {
#pragma unroll
        for (int mi = 0; mi < 8; ++mi)
#pragma unroll
            for (int r = 0; r < 4; ++r)
                rbuf[(wr * 128 + mi * 16 + kgrp * 4 + r) * 4 + wc] = rmx[mi][r];
    }
    __syncthreads();
    if (tid < 256) {
        const float v = fmaxf(fmaxf(rbuf[tid * 4 + 0], rbuf[tid * 4 + 1]),
                              fmaxf(rbuf[tid * 4 + 2], rbuf[tid * 4 + 3]));
        partial[((size_t)b * TT + tm * 256 + tid) * NT2 + tn] = v;
    }
}

// ---------------- K3: reduce partial maxes + gate_nn scale + final write ----------------
// 256 threads = 4 waves; one wave per row; reads bf16 PO, writes f32 out.
__global__ __launch_bounds__(256) void k3_scale(float* __restrict__ out,
                                                const unsigned short* __restrict__ po,
                                                const float* __restrict__ partial,
                                                const float* __restrict__ p_lsn,
                                                const float* __restrict__ p_lwn) {
    const int row = blockIdx.x * 4 + (threadIdx.x >> 6);
    const int lane = threadIdx.x & 63;
    const float sigma_nn = softplus_f(p_lsn[0]);
    const float w_nn = softplus_f(p_lwn[0]);

    float p = partial[(size_t)row * NT2 + (lane & 7)];
    p = fmaxf(p, __shfl_xor(p, 1));
    p = fmaxf(p, __shfl_xor(p, 2));
    p = fmaxf(p, __shfl_xor(p, 4));
    const float g = 1.0f + w_nn * tanh_fast(sigma_nn * 0.5f * (1.0f - p));

    const size_t base = (size_t)row * DD + lane * 8;
    ushort4 p0 = *reinterpret_cast<const ushort4*>(po + base);
    ushort4 p1 = *reinterpret_cast<const ushort4*>(po + base + 4);
    float4 o0, o1;
    o0.x = bf2f(p0.x) * g; o0.y = bf2f(p0.y) * g;
    o0.z = bf2f(p0.z) * g; o0.w = bf2f(p0.w) * g;
    o1.x = bf2f(p1.x) * g; o1.y = bf2f(p1.y) * g;
    o1.z = bf2f(p1.z) * g; o1.w = bf2f(p1.w) * g;
    *reinterpret_cast<float4*>(out + base) = o0;
    *reinterpret_cast<float4*>(out + base + 4) = o1;
}

extern "C" void kernel_launch(void* const* d_in, const int* in_sizes, int n_in,
                              void* d_out, int out_size, void* d_ws, size_t ws_size,
                              hipStream_t stream) {
    const float* x = (const float*)d_in[0];
    const float* ema_mean = (const float*)d_in[1];
    const float* ema_sq = (const float*)d_in[2];
    const float* ema_out = (const float*)d_in[3];
    const float* log_tau = (const float*)d_in[4];
    const float* log_beta_up = (const float*)d_in[5];
    const float* log_beta_dn = (const float*)d_in[6];
    const float* log_gamma = (const float*)d_in[7];
    const float* log_sigma_nn = (const float*)d_in[8];
    const float* log_w_nn = (const float*)d_in[9];

    // ws layout: XN bf16 [B*T*D] (16.78 MB) | PO bf16 [B*T*D] (16.78 MB)
    //            | partial f32[B*T][NT2] (512 KB) | inv_std f32[512] | ema_n f32[512]
    char* ws = (char*)d_ws;
    unsigned short* XN = (unsigned short*)ws;
    unsigned short* PO = (unsigned short*)(ws + 16777216);
    float* partial = (float*)(ws + 33554432);
    float* inv_std = (float*)(ws + 33554432 + 524288);
    float* ema_n = (float*)(ws + 33554432 + 524288 + 2048);
    float* out = (float*)d_out;

    hipLaunchKernelGGL(k0_prep, dim3(1), dim3(512), 0, stream, ema_mean, ema_sq, ema_out,
                       inv_std, ema_n);
    hipLaunchKernelGGL(k1_elem, dim3(BB * TT / 4), dim3(256), 0, stream, x, ema_mean, inv_std,
                       ema_n, log_tau, log_beta_up, log_beta_dn, log_gamma, XN, PO);
    hipLaunchKernelGGL(k2_nn, dim3(BB * 64), dim3(512), 0, stream, XN, partial);
    hipLaunchKernelGGL(k3_scale, dim3(BB * TT / 4), dim3(256), 0, stream, out, PO, partial,
                       log_sigma_nn, log_w_nn);
}

// Round 11
// 70.501 us; speedup vs baseline: 1.1094x; 1.1072x over previous
//
#include <hip/hip_runtime.h>
#include <hip/hip_bf16.h>
#include <math.h>

#define BB 8
#define TT 2048
#define DD 512
#define NSL 24  // partial slots: 0..15 = row-max by tn, 16..23 = col-max by tm

typedef __attribute__((ext_vector_type(8))) short bf16x8;
typedef __attribute__((ext_vector_type(4))) float f32x4;

__device__ inline float softplus_f(float v) { return log1pf(expf(v)); }

// fast tanh: 1 - 2/(exp2(2*log2e*y)+1); v_exp_f32 + v_rcp_f32, ~1e-6 rel err
__device__ inline float tanh_fast(float y) {
    float e = __builtin_amdgcn_exp2f(y * 2.8853900817779268f);
    return 1.0f - 2.0f * __builtin_amdgcn_rcpf(e + 1.0f);
}
__device__ inline float exp_fast(float y) {
    return __builtin_amdgcn_exp2f(y * 1.4426950408889634f);
}

// f32 -> bf16 via compiler cast (emits v_cvt_pk_bf16_f32 pairs; m240)
__device__ inline unsigned short cvt_bf16(float f) {
    __hip_bfloat16 h = (__hip_bfloat16)f;
    return *reinterpret_cast<unsigned short*>(&h);
}
__device__ inline float bf2f(unsigned short h) {
    unsigned int u = ((unsigned int)h) << 16;
    return __uint_as_float(u);
}

__device__ inline void load_lds16(const void* g, void* l) {
    __builtin_amdgcn_global_load_lds(
        (const __attribute__((address_space(1))) unsigned int*)g,
        (__attribute__((address_space(3))) unsigned int*)l, 16, 0, 0);
}

// ---------------- K0: per-channel prep (inv_std, normalized ema_out) ----------------
__global__ __launch_bounds__(512) void k0_prep(const float* __restrict__ ema_mean,
                                               const float* __restrict__ ema_sq,
                                               const float* __restrict__ ema_out,
                                               float* __restrict__ inv_std,
                                               float* __restrict__ ema_n) {
    __shared__ float red[8];
    int t = threadIdx.x;  // 512 threads, one per channel
    float m = ema_mean[t];
    float v = ema_sq[t] - m * m;
    v = fmaxf(v, 1e-4f);
    inv_std[t] = 1.0f / (sqrtf(v) + 1e-5f);

    float e = ema_out[t];
    float s = e * e;
#pragma unroll
    for (int off = 32; off; off >>= 1) s += __shfl_xor(s, off);
    if ((t & 63) == 0) red[t >> 6] = s;
    __syncthreads();
    if (t == 0) {
        float tot = 0.f;
        for (int i = 0; i < 8; ++i) tot += red[i];
        red[0] = 1.0f / fmaxf(sqrtf(tot), 1e-12f);
    }
    __syncthreads();
    ema_n[t] = e * red[0];
}

// ---------------- K1: per-row elementwise + reductions ----------------
// 256 threads = 4 waves; one wave per row of D=512; 8 elems/thread.
__global__ __launch_bounds__(256) void k1_elem(
    const float* __restrict__ x, const float* __restrict__ ema_mean,
    const float* __restrict__ inv_std, const float* __restrict__ ema_n,
    const float* __restrict__ p_log_tau, const float* __restrict__ p_lbu,
    const float* __restrict__ p_lbd, const float* __restrict__ p_lg,
    unsigned short* __restrict__ xn, unsigned short* __restrict__ po) {
    const int row = blockIdx.x * 4 + (threadIdx.x >> 6);
    const int lane = threadIdx.x & 63;
    const size_t base = (size_t)row * DD;

    const float tau = expf(p_log_tau[0]);
    const float beta_up = softplus_f(p_lbu[0]);
    const float beta_dn = softplus_f(p_lbd[0]);
    const float gamma = softplus_f(p_lg[0]);

    float xv[8], pg[8];
    float sx2 = 0.f, so2 = 0.f, sod = 0.f;
#pragma unroll
    for (int c = 0; c < 2; ++c) {
        const int j0 = c * 256 + lane * 4;
        float4 xx = *reinterpret_cast<const float4*>(x + base + j0);
        float4 mm = *reinterpret_cast<const float4*>(ema_mean + j0);
        float4 ii = *reinterpret_cast<const float4*>(inv_std + j0);
        float4 eo = *reinterpret_cast<const float4*>(ema_n + j0);
        float vv[4] = {xx.x, xx.y, xx.z, xx.w};
        float vm[4] = {mm.x, mm.y, mm.z, mm.w};
        float vi[4] = {ii.x, ii.y, ii.z, ii.w};
        float ve[4] = {eo.x, eo.y, eo.z, eo.w};
#pragma unroll
        for (int q = 0; q < 4; ++q) {
            const int e = c * 4 + q;
            float xf = vv[q];
            xv[e] = xf;
            float x3 = xf * xf * xf;
            float gl = 0.5f * xf * (1.0f + tanh_fast(0.7978845608028654f * (xf + 0.044715f * x3)));
            float z = (xf - vm[q]) * vi[q];
            float th = tanh_fast(gamma * z);
            float up = beta_up * fmaxf(th, 0.0f);
            float dn = beta_dn * fmaxf(-th, 0.0f);
            float gh = fminf(fmaxf(1.0f + up - dn, 0.05f), 8.0f);
            pg[e] = gl * gh;
            sx2 += xf * xf;
            so2 += gl * gl;
            sod += gl * ve[q];
        }
    }
#pragma unroll
    for (int off = 32; off; off >>= 1) {
        sx2 += __shfl_xor(sx2, off);
        so2 += __shfl_xor(so2, off);
        sod += __shfl_xor(sod, off);
    }
    const float inv_xnorm = __builtin_amdgcn_rcpf(fmaxf(sqrtf(sx2), 1e-12f));
    float cosv = sod * __builtin_amdgcn_rcpf(fmaxf(sqrtf(so2), 1e-12f));
    cosv = fminf(fmaxf(cosv, -1.0f), 1.0f);
    const float gcos = exp_fast(-tau * cosv);

#pragma unroll
    for (int c = 0; c < 2; ++c) {
        const int j0 = c * 256 + lane * 4;
        ushort4 pb;
        pb.x = cvt_bf16(pg[c * 4 + 0] * gcos);
        pb.y = cvt_bf16(pg[c * 4 + 1] * gcos);
        pb.z = cvt_bf16(pg[c * 4 + 2] * gcos);
        pb.w = cvt_bf16(pg[c * 4 + 3] * gcos);
        *reinterpret_cast<ushort4*>(po + base + j0) = pb;
        ushort4 xb;
        xb.x = cvt_bf16(xv[c * 4 + 0] * inv_xnorm);
        xb.y = cvt_bf16(xv[c * 4 + 1] * inv_xnorm);
        xb.z = cvt_bf16(xv[c * 4 + 2] * inv_xnorm);
        xb.w = cvt_bf16(xv[c * 4 + 3] * inv_xnorm);
        *reinterpret_cast<ushort4*>(xn + base + j0) = xb;
    }
}

// ---------------- K2: symmetric sim row/col max, 256x128 tiles, 2 blocks/CU ----
// Tiles (tm: 256-row panel 0..7, tn: 128-col panel 0..15) with tn >= 2*tm
// (72/batch, 0.56x the full-matrix FLOPs; duplicate (i>j) cells are harmless —
// max is idempotent). Each tile emits row-max -> slot tn and col-max -> slot
// 16+tm of partial[row][24]. Diagonal cells masked: rl == cl + 128*(tn-2tm).
// 512 threads = 8 waves (4 row x 2 col), per-wave 64x64 out (acc 64 VGPR,
// ~120 total, __launch_bounds__(512,4)): with 72-KB LDS (3 slots x 24 KB) TWO
// blocks co-reside per CU -> 4 waves/SIMD; the other block's waves fill this
// block's barrier/convoy gaps (m114) — the missing ingredient of R8-R10
// (1 block/CU, 2 waves/SIMD, Occupancy 18%).
// Pipeline: stage 2 K-tiles ahead (3 loads/thread/tile), boundary vmcnt(3) +
// raw s_barrier (counted, never drain-0 mid-loop). Swizzle: 2 logical 64B rows
// per 128B LDS row, byte ^= ((sup&7)<<4) — R8-PMC-verified 0 conflicts;
// gload_lds dest linear, global source inverse-swizzled (rule 21).
__global__ __launch_bounds__(512, 4) void k2_nn(const unsigned short* __restrict__ xn,
                                                float* __restrict__ partial) {
    __shared__ char lds[73728];  // 3 slots x (A 16 KB | B 8 KB)

    const int tid = threadIdx.x;
    const int wave = tid >> 6;
    const int lane = tid & 63;
    const int r15 = lane & 15;
    const int kgrp = lane >> 4;
    const int wr = wave >> 1;  // 0..3 (row quarter of 256)
    const int wc = wave & 1;   // 0..1 (col half of 128)

    const int bid = blockIdx.x;
    const int b = bid & 7;  // XCD pin (576 % 8 == 0 -> bijective)
    int t = bid >> 3;       // 0..71
    int tm = 0;
    while (t >= 16 - 2 * tm) { t -= 16 - 2 * tm; ++tm; }
    const int tn = 2 * tm + t;

    const size_t bbase = (size_t)b * TT * DD;
    const unsigned short* Ag = xn + bbase + (size_t)tm * 256 * DD;
    const unsigned short* Bg = xn + bbase + (size_t)tn * 128 * DD;

    f32x4 acc[4][4];
#pragma unroll
    for (int i = 0; i < 4; ++i)
#pragma unroll
        for (int j = 0; j < 4; ++j) acc[i][j] = (f32x4){0.f, 0.f, 0.f, 0.f};

    // stage one K-tile (BK=32): A 2 loads + B 1 load per thread
    auto stage = [&](int slot, int kt) {
#pragma unroll
        for (int l = 0; l < 2; ++l) {
            const int o = l * 8192 + tid * 16;
            const int sup = o >> 7;
            const int w = (o & 127) ^ ((sup & 7) << 4);
            const int row = sup * 2 + (w >> 6);
            const int ce = (w & 63) >> 1;
            load_lds16(Ag + (size_t)row * DD + kt * 32 + ce, lds + slot * 24576 + o);
        }
        {
            const int o = tid * 16;
            const int sup = o >> 7;
            const int w = (o & 127) ^ ((sup & 7) << 4);
            const int row = sup * 2 + (w >> 6);
            const int ce = (w & 63) >> 1;
            load_lds16(Bg + (size_t)row * DD + kt * 32 + ce, lds + slot * 24576 + 16384 + o);
        }
    };

#define LADDR(R) \
    (((R) >> 1) * 128 + (((((R) & 1) << 6) + (kgrp << 4)) ^ ((((R) >> 1) & 7) << 4)))

    auto compute = [&](int slot) {
        const char* sA = lds + slot * 24576;
        const char* sB = sA + 16384;
        bf16x8 av[4], bv[4];
#pragma unroll
        for (int ni = 0; ni < 4; ++ni)
            bv[ni] = *(const bf16x8*)(sB + LADDR(wc * 64 + ni * 16 + r15));
#pragma unroll
        for (int mi = 0; mi < 4; ++mi)
            av[mi] = *(const bf16x8*)(sA + LADDR(wr * 64 + mi * 16 + r15));
        __builtin_amdgcn_s_setprio(1);
#pragma unroll
        for (int mi = 0; mi < 4; ++mi)
#pragma unroll
            for (int ni = 0; ni < 4; ++ni)
                acc[mi][ni] = __builtin_amdgcn_mfma_f32_16x16x32_bf16(av[mi], bv[ni],
                                                                      acc[mi][ni], 0, 0, 0);
        __builtin_amdgcn_s_setprio(0);
    };
#undef LADDR

    // prologue: stage tiles 0,1 (6 loads); vmcnt(3) -> tile 0 landed
    stage(0, 0);
    stage(1, 1);
    asm volatile("s_waitcnt vmcnt(3)" ::: "memory");
    __builtin_amdgcn_s_barrier();
    __builtin_amdgcn_sched_barrier(0);

#pragma unroll
    for (int kt = 0; kt < 16; ++kt) {
        if (kt + 2 < 16) stage((kt + 2) % 3, kt + 2);  // overwrites tile kt-1's slot
        compute(kt % 3);
        if (kt < 15) {
            if (kt <= 13)
                asm volatile("s_waitcnt vmcnt(3)" ::: "memory");  // tile kt+1 landed
            else
                asm volatile("s_waitcnt vmcnt(0)" ::: "memory");  // tail drain
            __builtin_amdgcn_s_barrier();
            __builtin_amdgcn_sched_barrier(0);
        }
    }

    // ---- epilogue ----
    // D layout: col cl = wc*64 + ni*16 + r15, row rl = wr*64 + mi*16 + kgrp*4 + rr
    const int doff = 128 * (tn - 2 * tm);
    const bool isdiag = (doff == 0) || (doff == 128);
    if (isdiag) {
#pragma unroll
        for (int mi = 0; mi < 4; ++mi)
#pragma unroll
            for (int ni = 0; ni < 4; ++ni)
#pragma unroll
                for (int rr = 0; rr < 4; ++rr) {
                    const int rl = wr * 64 + mi * 16 + kgrp * 4 + rr;
                    const int cl = wc * 64 + ni * 16 + r15;
                    if (rl == cl + doff) acc[mi][ni][rr] = -2.0f;
                }
    }
    // row-max: fold ni, shfl over the 16 col-lanes
    float rmx[4][4];
#pragma unroll
    for (int mi = 0; mi < 4; ++mi)
#pragma unroll
        for (int rr = 0; rr < 4; ++rr) {
            float v = fmaxf(fmaxf(acc[mi][0][rr], acc[mi][1][rr]),
                            fmaxf(acc[mi][2][rr], acc[mi][3][rr]));
            v = fmaxf(v, __shfl_xor(v, 1));
            v = fmaxf(v, __shfl_xor(v, 2));
            v = fmaxf(v, __shfl_xor(v, 4));
            v = fmaxf(v, __shfl_xor(v, 8));
            rmx[mi][rr] = v;
        }
    // col-max: fold mi,rr in-lane, shfl across kgrp
    float cmx[4];
#pragma unroll
    for (int ni = 0; ni < 4; ++ni) {
        float v = -2.0f;
#pragma unroll
        for (int mi = 0; mi < 4; ++mi)
#pragma unroll
            for (int rr = 0; rr < 4; ++rr) v = fmaxf(v, acc[mi][ni][rr]);
        v = fmaxf(v, __shfl_xor(v, 16));
        v = fmaxf(v, __shfl_xor(v, 32));
        cmx[ni] = v;
    }
    __syncthreads();  // all LDS tile reads + loads done; alias reduce bufs onto lds
    float* rbuf = (float*)lds;           // [256][2] (wc)
    float* cbuf = (float*)(lds + 2048);  // [128][4] (wr)
    if (r15 == 0) {
#pragma unroll
        for (int mi = 0; mi < 4; ++mi)
#pragma unroll
            for (int rr = 0; rr < 4; ++rr)
                rbuf[(wr * 64 + mi * 16 + kgrp * 4 + rr) * 2 + wc] = rmx[mi][rr];
    }
    if (kgrp == 0) {
#pragma unroll
        for (int ni = 0; ni < 4; ++ni)
            cbuf[(wc * 64 + ni * 16 + r15) * 4 + wr] = cmx[ni];
    }
    __syncthreads();
    if (tid < 256) {
        const float v = fmaxf(rbuf[tid * 2 + 0], rbuf[tid * 2 + 1]);
        partial[((size_t)b * TT + tm * 256 + tid) * NSL + tn] = v;
    } else if (tid < 384) {
        const int c = tid - 256;
        const float v = fmaxf(fmaxf(cbuf[c * 4 + 0], cbuf[c * 4 + 1]),
                              fmaxf(cbuf[c * 4 + 2], cbuf[c * 4 + 3]));
        partial[((size_t)b * TT + tn * 128 + c) * NSL + 16 + tm] = v;
    }
}

// ---------------- K3: reduce partial maxes + gate_nn scale + final write ----------------
// 256 threads = 4 waves; one wave per row; reads bf16 PO, writes f32 out.
// Valid slots: A-side tn >= 2*tmr (tmr = row-panel), B-side tm <= tnr>>1.
__global__ __launch_bounds__(256) void k3_scale(float* __restrict__ out,
                                                const unsigned short* __restrict__ po,
                                                const float* __restrict__ partial,
                                                const float* __restrict__ p_lsn,
                                                const float* __restrict__ p_lwn) {
    const int row = blockIdx.x * 4 + (threadIdx.x >> 6);
    const int lane = threadIdx.x & 63;
    const float sigma_nn = softplus_f(p_lsn[0]);
    const float w_nn = softplus_f(p_lwn[0]);

    const int rb = row & (TT - 1);
    const int tmr = rb >> 8;  // 256-row panel of this row
    const int tnr = rb >> 7;  // 128-col panel of this row
    const int idx = lane & 31;
    float v = -2.0f;
    if (idx < 16) {
        if (idx >= 2 * tmr) v = partial[(size_t)row * NSL + idx];
    } else if (idx < NSL) {
        if (idx - 16 <= (tnr >> 1)) v = partial[(size_t)row * NSL + idx];
    }
    v = fmaxf(v, __shfl_xor(v, 1));
    v = fmaxf(v, __shfl_xor(v, 2));
    v = fmaxf(v, __shfl_xor(v, 4));
    v = fmaxf(v, __shfl_xor(v, 8));
    v = fmaxf(v, __shfl_xor(v, 16));
    const float g = 1.0f + w_nn * tanh_fast(sigma_nn * 0.5f * (1.0f - v));

    const size_t base = (size_t)row * DD + lane * 8;
    ushort4 p0 = *reinterpret_cast<const ushort4*>(po + base);
    ushort4 p1 = *reinterpret_cast<const ushort4*>(po + base + 4);
    float4 o0, o1;
    o0.x = bf2f(p0.x) * g; o0.y = bf2f(p0.y) * g;
    o0.z = bf2f(p0.z) * g; o0.w = bf2f(p0.w) * g;
    o1.x = bf2f(p1.x) * g; o1.y = bf2f(p1.y) * g;
    o1.z = bf2f(p1.z) * g; o1.w = bf2f(p1.w) * g;
    *reinterpret_cast<float4*>(out + base) = o0;
    *reinterpret_cast<float4*>(out + base + 4) = o1;
}

extern "C" void kernel_launch(void* const* d_in, const int* in_sizes, int n_in,
                              void* d_out, int out_size, void* d_ws, size_t ws_size,
                              hipStream_t stream) {
    const float* x = (const float*)d_in[0];
    const float* ema_mean = (const float*)d_in[1];
    const float* ema_sq = (const float*)d_in[2];
    const float* ema_out = (const float*)d_in[3];
    const float* log_tau = (const float*)d_in[4];
    const float* log_beta_up = (const float*)d_in[5];
    const float* log_beta_dn = (const float*)d_in[6];
    const float* log_gamma = (const float*)d_in[7];
    const float* log_sigma_nn = (const float*)d_in[8];
    const float* log_w_nn = (const float*)d_in[9];

    // ws layout: XN bf16 [B*T*D] (16.78 MB) | PO bf16 [B*T*D] (16.78 MB)
    //            | partial f32[B*T][NSL] (1.57 MB) | inv_std f32[512] | ema_n f32[512]
    char* ws = (char*)d_ws;
    unsigned short* XN = (unsigned short*)ws;
    unsigned short* PO = (unsigned short*)(ws + 16777216);
    float* partial = (float*)(ws + 33554432);
    float* inv_std = (float*)(ws + 33554432 + 1572864);
    float* ema_n = (float*)(ws + 33554432 + 1572864 + 2048);
    float* out = (float*)d_out;

    hipLaunchKernelGGL(k0_prep, dim3(1), dim3(512), 0, stream, ema_mean, ema_sq, ema_out,
                       inv_std, ema_n);
    hipLaunchKernelGGL(k1_elem, dim3(BB * TT / 4), dim3(256), 0, stream, x, ema_mean, inv_std,
                       ema_n, log_tau, log_beta_up, log_beta_dn, log_gamma, XN, PO);
    hipLaunchKernelGGL(k2_nn, dim3(BB * 72), dim3(512), 0, stream, XN, partial);
    hipLaunchKernelGGL(k3_scale, dim3(BB * TT / 4), dim3(256), 0, stream, out, PO, partial,
                       log_sigma_nn, log_w_nn);
}

// Round 12
// 61.644 us; speedup vs baseline: 1.2688x; 1.1437x over previous
//
#include <hip/hip_runtime.h>
#include <hip/hip_bf16.h>
#include <math.h>

#define BB 8
#define TT 2048
#define DD 512
#define NSL 24  // partial slots: 0..15 = row-max by tn, 16..23 = col-max by tm

typedef __attribute__((ext_vector_type(8))) short bf16x8;
typedef __attribute__((ext_vector_type(4))) float f32x4;
typedef __attribute__((ext_vector_type(4))) int i32x4;

__device__ inline float softplus_f(float v) { return log1pf(expf(v)); }

// fast tanh: 1 - 2/(exp2(2*log2e*y)+1); v_exp_f32 + v_rcp_f32, ~1e-6 rel err
__device__ inline float tanh_fast(float y) {
    float e = __builtin_amdgcn_exp2f(y * 2.8853900817779268f);
    return 1.0f - 2.0f * __builtin_amdgcn_rcpf(e + 1.0f);
}
__device__ inline float exp_fast(float y) {
    return __builtin_amdgcn_exp2f(y * 1.4426950408889634f);
}

// f32 -> bf16 via compiler cast (emits v_cvt_pk_bf16_f32 pairs; m240)
__device__ inline unsigned short cvt_bf16(float f) {
    __hip_bfloat16 h = (__hip_bfloat16)f;
    return *reinterpret_cast<unsigned short*>(&h);
}
__device__ inline float bf2f(unsigned short h) {
    unsigned int u = ((unsigned int)h) << 16;
    return __uint_as_float(u);
}

__device__ inline void load_lds16(const void* g, void* l) {
    __builtin_amdgcn_global_load_lds(
        (const __attribute__((address_space(1))) unsigned int*)g,
        (__attribute__((address_space(3))) unsigned int*)l, 16, 0, 0);
}

// ---------------- K0: per-channel prep (inv_std, normalized ema_out) ----------------
__global__ __launch_bounds__(512) void k0_prep(const float* __restrict__ ema_mean,
                                               const float* __restrict__ ema_sq,
                                               const float* __restrict__ ema_out,
                                               float* __restrict__ inv_std,
                                               float* __restrict__ ema_n) {
    __shared__ float red[8];
    int t = threadIdx.x;  // 512 threads, one per channel
    float m = ema_mean[t];
    float v = ema_sq[t] - m * m;
    v = fmaxf(v, 1e-4f);
    inv_std[t] = 1.0f / (sqrtf(v) + 1e-5f);

    float e = ema_out[t];
    float s = e * e;
#pragma unroll
    for (int off = 32; off; off >>= 1) s += __shfl_xor(s, off);
    if ((t & 63) == 0) red[t >> 6] = s;
    __syncthreads();
    if (t == 0) {
        float tot = 0.f;
        for (int i = 0; i < 8; ++i) tot += red[i];
        red[0] = 1.0f / fmaxf(sqrtf(tot), 1e-12f);
    }
    __syncthreads();
    ema_n[t] = e * red[0];
}

// ---------------- K1: per-row elementwise + reductions ----------------
// 256 threads = 4 waves; one wave per row of D=512; 8 elems/thread.
// Writes XN8 (normalized x quantized to int8 * 127) and PO (bf16 pre-gated).
__global__ __launch_bounds__(256) void k1_elem(
    const float* __restrict__ x, const float* __restrict__ ema_mean,
    const float* __restrict__ inv_std, const float* __restrict__ ema_n,
    const float* __restrict__ p_log_tau, const float* __restrict__ p_lbu,
    const float* __restrict__ p_lbd, const float* __restrict__ p_lg,
    unsigned char* __restrict__ xn8, unsigned short* __restrict__ po) {
    const int row = blockIdx.x * 4 + (threadIdx.x >> 6);
    const int lane = threadIdx.x & 63;
    const size_t base = (size_t)row * DD;

    const float tau = expf(p_log_tau[0]);
    const float beta_up = softplus_f(p_lbu[0]);
    const float beta_dn = softplus_f(p_lbd[0]);
    const float gamma = softplus_f(p_lg[0]);

    float xv[8], pg[8];
    float sx2 = 0.f, so2 = 0.f, sod = 0.f;
#pragma unroll
    for (int c = 0; c < 2; ++c) {
        const int j0 = c * 256 + lane * 4;
        float4 xx = *reinterpret_cast<const float4*>(x + base + j0);
        float4 mm = *reinterpret_cast<const float4*>(ema_mean + j0);
        float4 ii = *reinterpret_cast<const float4*>(inv_std + j0);
        float4 eo = *reinterpret_cast<const float4*>(ema_n + j0);
        float vv[4] = {xx.x, xx.y, xx.z, xx.w};
        float vm[4] = {mm.x, mm.y, mm.z, mm.w};
        float vi[4] = {ii.x, ii.y, ii.z, ii.w};
        float ve[4] = {eo.x, eo.y, eo.z, eo.w};
#pragma unroll
        for (int q = 0; q < 4; ++q) {
            const int e = c * 4 + q;
            float xf = vv[q];
            xv[e] = xf;
            float x3 = xf * xf * xf;
            float gl = 0.5f * xf * (1.0f + tanh_fast(0.7978845608028654f * (xf + 0.044715f * x3)));
            float z = (xf - vm[q]) * vi[q];
            float th = tanh_fast(gamma * z);
            float up = beta_up * fmaxf(th, 0.0f);
            float dn = beta_dn * fmaxf(-th, 0.0f);
            float gh = fminf(fmaxf(1.0f + up - dn, 0.05f), 8.0f);
            pg[e] = gl * gh;
            sx2 += xf * xf;
            so2 += gl * gl;
            sod += gl * ve[q];
        }
    }
#pragma unroll
    for (int off = 32; off; off >>= 1) {
        sx2 += __shfl_xor(sx2, off);
        so2 += __shfl_xor(so2, off);
        sod += __shfl_xor(sod, off);
    }
    const float qscale = 127.0f * __builtin_amdgcn_rcpf(fmaxf(sqrtf(sx2), 1e-12f));
    float cosv = sod * __builtin_amdgcn_rcpf(fmaxf(sqrtf(so2), 1e-12f));
    cosv = fminf(fmaxf(cosv, -1.0f), 1.0f);
    const float gcos = exp_fast(-tau * cosv);

#pragma unroll
    for (int c = 0; c < 2; ++c) {
        const int j0 = c * 256 + lane * 4;
        ushort4 pb;
        pb.x = cvt_bf16(pg[c * 4 + 0] * gcos);
        pb.y = cvt_bf16(pg[c * 4 + 1] * gcos);
        pb.z = cvt_bf16(pg[c * 4 + 2] * gcos);
        pb.w = cvt_bf16(pg[c * 4 + 3] * gcos);
        *reinterpret_cast<ushort4*>(po + base + j0) = pb;
        int q0 = __float2int_rn(xv[c * 4 + 0] * qscale);
        int q1 = __float2int_rn(xv[c * 4 + 1] * qscale);
        int q2 = __float2int_rn(xv[c * 4 + 2] * qscale);
        int q3 = __float2int_rn(xv[c * 4 + 3] * qscale);
        int pk = (q0 & 255) | ((q1 & 255) << 8) | ((q2 & 255) << 16) | (q3 << 24);
        *reinterpret_cast<int*>(xn8 + base + j0) = pk;
    }
}

// ---------------- K2: symmetric sim row/col max, int8 MFMA, 256x128 tiles ----
// Same proven R11 skeleton (2 blocks/CU, 4 waves/SIMD, 3-slot counted-vmcnt
// pipeline, 0-conflict swizzle) with int8 numerics: mfma_i32_16x16x64_i8 is
// 2x bf16 rate AND 1 B/elem halves LDS-read + staged bytes -> both floors
// drop (MFMA 9.3->4.7 us, LDS 11.5->5.8 us). BK=64 i8 bytes == BK=32 bf16
// bytes: addressing identical to R11. Fragment: 16 consecutive k-bytes/lane
// at byte col kgrp*16 (one K=64 step per tile). Epilogue scales by 1/127^2.
__global__ __launch_bounds__(512, 4) void k2_nn(const unsigned char* __restrict__ xn8,
                                                float* __restrict__ partial) {
    __shared__ char lds[73728];  // 3 slots x (A 16 KB | B 8 KB)

    const int tid = threadIdx.x;
    const int wave = tid >> 6;
    const int lane = tid & 63;
    const int r15 = lane & 15;
    const int kgrp = lane >> 4;
    const int wr = wave >> 1;  // 0..3 (row quarter of 256)
    const int wc = wave & 1;   // 0..1 (col half of 128)

    const int bid = blockIdx.x;
    const int b = bid & 7;  // XCD pin (576 % 8 == 0 -> bijective)
    int t = bid >> 3;       // 0..71
    int tm = 0;
    while (t >= 16 - 2 * tm) { t -= 16 - 2 * tm; ++tm; }
    const int tn = 2 * tm + t;

    const size_t bbase = (size_t)b * TT * DD;
    const unsigned char* Ag = xn8 + bbase + (size_t)tm * 256 * DD;
    const unsigned char* Bg = xn8 + bbase + (size_t)tn * 128 * DD;

    i32x4 acc[4][4];
#pragma unroll
    for (int i = 0; i < 4; ++i)
#pragma unroll
        for (int j = 0; j < 4; ++j) acc[i][j] = (i32x4){0, 0, 0, 0};

    // stage one K-tile (64 i8 cols): A 2 loads + B 1 load per thread
    auto stage = [&](int slot, int kt) {
#pragma unroll
        for (int l = 0; l < 2; ++l) {
            const int o = l * 8192 + tid * 16;
            const int sup = o >> 7;
            const int w = (o & 127) ^ ((sup & 7) << 4);
            const int row = sup * 2 + (w >> 6);
            const int cb = w & 63;
            load_lds16(Ag + (size_t)row * DD + kt * 64 + cb, lds + slot * 24576 + o);
        }
        {
            const int o = tid * 16;
            const int sup = o >> 7;
            const int w = (o & 127) ^ ((sup & 7) << 4);
            const int row = sup * 2 + (w >> 6);
            const int cb = w & 63;
            load_lds16(Bg + (size_t)row * DD + kt * 64 + cb, lds + slot * 24576 + 16384 + o);
        }
    };

#define LADDR(R) \
    (((R) >> 1) * 128 + (((((R) & 1) << 6) + (kgrp << 4)) ^ ((((R) >> 1) & 7) << 4)))

    auto compute = [&](int slot) {
        const char* sA = lds + slot * 24576;
        const char* sB = sA + 16384;
        i32x4 av[4], bv[4];
#pragma unroll
        for (int ni = 0; ni < 4; ++ni)
            bv[ni] = *(const i32x4*)(sB + LADDR(wc * 64 + ni * 16 + r15));
#pragma unroll
        for (int mi = 0; mi < 4; ++mi)
            av[mi] = *(const i32x4*)(sA + LADDR(wr * 64 + mi * 16 + r15));
        __builtin_amdgcn_s_setprio(1);
#pragma unroll
        for (int mi = 0; mi < 4; ++mi)
#pragma unroll
            for (int ni = 0; ni < 4; ++ni)
                acc[mi][ni] = __builtin_amdgcn_mfma_i32_16x16x64_i8(av[mi], bv[ni],
                                                                    acc[mi][ni], 0, 0, 0);
        __builtin_amdgcn_s_setprio(0);
    };
#undef LADDR

    // prologue: stage tiles 0,1 (6 loads); vmcnt(3) -> tile 0 landed
    stage(0, 0);
    stage(1, 1);
    asm volatile("s_waitcnt vmcnt(3)" ::: "memory");
    __builtin_amdgcn_s_barrier();
    __builtin_amdgcn_sched_barrier(0);

#pragma unroll
    for (int kt = 0; kt < 8; ++kt) {
        if (kt + 2 < 8) stage((kt + 2) % 3, kt + 2);  // overwrites tile kt-1's slot
        compute(kt % 3);
        if (kt < 7) {
            if (kt <= 5)
                asm volatile("s_waitcnt vmcnt(3)" ::: "memory");  // tile kt+1 landed
            else
                asm volatile("s_waitcnt vmcnt(0)" ::: "memory");  // tail drain
            __builtin_amdgcn_s_barrier();
            __builtin_amdgcn_sched_barrier(0);
        }
    }

    // ---- epilogue ----
    // D layout: col cl = wc*64 + ni*16 + r15, row rl = wr*64 + mi*16 + kgrp*4 + rr
    const float inv_qq = 1.0f / (127.0f * 127.0f);
    const int doff = 128 * (tn - 2 * tm);
    const bool isdiag = (doff == 0) || (doff == 128);
    float accf[4][4][4];
#pragma unroll
    for (int mi = 0; mi < 4; ++mi)
#pragma unroll
        for (int ni = 0; ni < 4; ++ni)
#pragma unroll
            for (int rr = 0; rr < 4; ++rr) {
                float e = (float)acc[mi][ni][rr] * inv_qq;
                if (isdiag) {
                    const int rl = wr * 64 + mi * 16 + kgrp * 4 + rr;
                    const int cl = wc * 64 + ni * 16 + r15;
                    if (rl == cl + doff) e = -2.0f;
                }
                accf[mi][ni][rr] = e;
            }
    // row-max: fold ni, shfl over the 16 col-lanes
    float rmx[4][4];
#pragma unroll
    for (int mi = 0; mi < 4; ++mi)
#pragma unroll
        for (int rr = 0; rr < 4; ++rr) {
            float v = fmaxf(fmaxf(accf[mi][0][rr], accf[mi][1][rr]),
                            fmaxf(accf[mi][2][rr], accf[mi][3][rr]));
            v = fmaxf(v, __shfl_xor(v, 1));
            v = fmaxf(v, __shfl_xor(v, 2));
            v = fmaxf(v, __shfl_xor(v, 4));
            v = fmaxf(v, __shfl_xor(v, 8));
            rmx[mi][rr] = v;
        }
    // col-max: fold mi,rr in-lane, shfl across kgrp
    float cmx[4];
#pragma unroll
    for (int ni = 0; ni < 4; ++ni) {
        float v = -2.0f;
#pragma unroll
        for (int mi = 0; mi < 4; ++mi)
#pragma unroll
            for (int rr = 0; rr < 4; ++rr) v = fmaxf(v, accf[mi][ni][rr]);
        v = fmaxf(v, __shfl_xor(v, 16));
        v = fmaxf(v, __shfl_xor(v, 32));
        cmx[ni] = v;
    }
    __syncthreads();  // all LDS tile reads + loads done; alias reduce bufs onto lds
    float* rbuf = (float*)lds;           // [256][2] (wc)
    float* cbuf = (float*)(lds + 2048);  // [128][4] (wr)
    if (r15 == 0) {
#pragma unroll
        for (int mi = 0; mi < 4; ++mi)
#pragma unroll
            for (int rr = 0; rr < 4; ++rr)
                rbuf[(wr * 64 + mi * 16 + kgrp * 4 + rr) * 2 + wc] = rmx[mi][rr];
    }
    if (kgrp == 0) {
#pragma unroll
        for (int ni = 0; ni < 4; ++ni)
            cbuf[(wc * 64 + ni * 16 + r15) * 4 + wr] = cmx[ni];
    }
    __syncthreads();
    if (tid < 256) {
        const float v = fmaxf(rbuf[tid * 2 + 0], rbuf[tid * 2 + 1]);
        partial[((size_t)b * TT + tm * 256 + tid) * NSL + tn] = v;
    } else if (tid < 384) {
        const int c = tid - 256;
        const float v = fmaxf(fmaxf(cbuf[c * 4 + 0], cbuf[c * 4 + 1]),
                              fmaxf(cbuf[c * 4 + 2], cbuf[c * 4 + 3]));
        partial[((size_t)b * TT + tn * 128 + c) * NSL + 16 + tm] = v;
    }
}

// ---------------- K3: reduce partial maxes + gate_nn scale + final write ----------------
// 256 threads = 4 waves; one wave per row; reads bf16 PO, writes f32 out.
// Valid slots: A-side tn >= 2*tmr (tmr = row-panel), B-side tm <= tnr>>1.
__global__ __launch_bounds__(256) void k3_scale(float* __restrict__ out,
                                                const unsigned short* __restrict__ po,
                                                const float* __restrict__ partial,
                                                const float* __restrict__ p_lsn,
                                                const float* __restrict__ p_lwn) {
    const int row = blockIdx.x * 4 + (threadIdx.x >> 6);
    const int lane = threadIdx.x & 63;
    const float sigma_nn = softplus_f(p_lsn[0]);
    const float w_nn = softplus_f(p_lwn[0]);

    const int rb = row & (TT - 1);
    const int tmr = rb >> 8;  // 256-row panel of this row
    const int tnr = rb >> 7;  // 128-col panel of this row
    const int idx = lane & 31;
    float v = -2.0f;
    if (idx < 16) {
        if (idx >= 2 * tmr) v = partial[(size_t)row * NSL + idx];
    } else if (idx < NSL) {
        if (idx - 16 <= (tnr >> 1)) v = partial[(size_t)row * NSL + idx];
    }
    v = fmaxf(v, __shfl_xor(v, 1));
    v = fmaxf(v, __shfl_xor(v, 2));
    v = fmaxf(v, __shfl_xor(v, 4));
    v = fmaxf(v, __shfl_xor(v, 8));
    v = fmaxf(v, __shfl_xor(v, 16));
    const float g = 1.0f + w_nn * tanh_fast(sigma_nn * 0.5f * (1.0f - v));

    const size_t base = (size_t)row * DD + lane * 8;
    ushort4 p0 = *reinterpret_cast<const ushort4*>(po + base);
    ushort4 p1 = *reinterpret_cast<const ushort4*>(po + base + 4);
    float4 o0, o1;
    o0.x = bf2f(p0.x) * g; o0.y = bf2f(p0.y) * g;
    o0.z = bf2f(p0.z) * g; o0.w = bf2f(p0.w) * g;
    o1.x = bf2f(p1.x) * g; o1.y = bf2f(p1.y) * g;
    o1.z = bf2f(p1.z) * g; o1.w = bf2f(p1.w) * g;
    *reinterpret_cast<float4*>(out + base) = o0;
    *reinterpret_cast<float4*>(out + base + 4) = o1;
}

extern "C" void kernel_launch(void* const* d_in, const int* in_sizes, int n_in,
                              void* d_out, int out_size, void* d_ws, size_t ws_size,
                              hipStream_t stream) {
    const float* x = (const float*)d_in[0];
    const float* ema_mean = (const float*)d_in[1];
    const float* ema_sq = (const float*)d_in[2];
    const float* ema_out = (const float*)d_in[3];
    const float* log_tau = (const float*)d_in[4];
    const float* log_beta_up = (const float*)d_in[5];
    const float* log_beta_dn = (const float*)d_in[6];
    const float* log_gamma = (const float*)d_in[7];
    const float* log_sigma_nn = (const float*)d_in[8];
    const float* log_w_nn = (const float*)d_in[9];

    // ws layout: XN8 i8 [B*T*D] (8.39 MB) | PO bf16 [B*T*D] (16.78 MB)
    //            | partial f32[B*T][NSL] (1.57 MB) | inv_std f32[512] | ema_n f32[512]
    char* ws = (char*)d_ws;
    unsigned char* XN8 = (unsigned char*)ws;
    unsigned short* PO = (unsigned short*)(ws + 8388608);
    float* partial = (float*)(ws + 8388608 + 16777216);
    float* inv_std = (float*)(ws + 8388608 + 16777216 + 1572864);
    float* ema_n = (float*)(ws + 8388608 + 16777216 + 1572864 + 2048);
    float* out = (float*)d_out;

    hipLaunchKernelGGL(k0_prep, dim3(1), dim3(512), 0, stream, ema_mean, ema_sq, ema_out,
                       inv_std, ema_n);
    hipLaunchKernelGGL(k1_elem, dim3(BB * TT / 4), dim3(256), 0, stream, x, ema_mean, inv_std,
                       ema_n, log_tau, log_beta_up, log_beta_dn, log_gamma, XN8, PO);
    hipLaunchKernelGGL(k2_nn, dim3(BB * 72), dim3(512), 0, stream, XN8, partial);
    hipLaunchKernelGGL(k3_scale, dim3(BB * TT / 4), dim3(256), 0, stream, out, PO, partial,
                       log_sigma_nn, log_w_nn);
}

// Round 13
// 60.725 us; speedup vs baseline: 1.2881x; 1.0151x over previous
//
#include <hip/hip_runtime.h>
#include <hip/hip_bf16.h>
#include <math.h>

#define BB 8
#define TT 2048
#define DD 512
#define NSL 32  // slots: 0..15 row-max by tn; 16..31 col-max by tm (tm<p valid)

typedef __attribute__((ext_vector_type(8))) short bf16x8;
typedef __attribute__((ext_vector_type(4))) float f32x4;
typedef __attribute__((ext_vector_type(4))) int i32x4;

__device__ inline float softplus_f(float v) { return log1pf(expf(v)); }

// fast tanh: 1 - 2/(exp2(2*log2e*y)+1); v_exp_f32 + v_rcp_f32, ~1e-6 rel err
__device__ inline float tanh_fast(float y) {
    float e = __builtin_amdgcn_exp2f(y * 2.8853900817779268f);
    return 1.0f - 2.0f * __builtin_amdgcn_rcpf(e + 1.0f);
}
__device__ inline float exp_fast(float y) {
    return __builtin_amdgcn_exp2f(y * 1.4426950408889634f);
}

// f32 -> bf16 via compiler cast (emits v_cvt_pk_bf16_f32 pairs; m240)
__device__ inline unsigned short cvt_bf16(float f) {
    __hip_bfloat16 h = (__hip_bfloat16)f;
    return *reinterpret_cast<unsigned short*>(&h);
}
__device__ inline float bf2f(unsigned short h) {
    unsigned int u = ((unsigned int)h) << 16;
    return __uint_as_float(u);
}

__device__ inline void load_lds16(const void* g, void* l) {
    __builtin_amdgcn_global_load_lds(
        (const __attribute__((address_space(1))) unsigned int*)g,
        (__attribute__((address_space(3))) unsigned int*)l, 16, 0, 0);
}

// ---------------- K1: fused prep + per-row elementwise + reductions ----------------
// 256 threads = 4 waves; one wave per row of D=512; 8 elems/thread.
// inv_std computed inline (L2-hot ema arrays); ||ema_out|| per-wave reduce
// (each wave spans all 512 channels). Writes XN8 (int8-quantized normalized x)
// and PO (gelu*gate_hist*gate_cos, bf16).
__global__ __launch_bounds__(256) void k1_elem(
    const float* __restrict__ x, const float* __restrict__ ema_mean,
    const float* __restrict__ ema_sq, const float* __restrict__ ema_out,
    const float* __restrict__ p_log_tau, const float* __restrict__ p_lbu,
    const float* __restrict__ p_lbd, const float* __restrict__ p_lg,
    unsigned char* __restrict__ xn8, unsigned short* __restrict__ po) {
    const int row = blockIdx.x * 4 + (threadIdx.x >> 6);
    const int lane = threadIdx.x & 63;
    const size_t base = (size_t)row * DD;

    const float tau = expf(p_log_tau[0]);
    const float beta_up = softplus_f(p_lbu[0]);
    const float beta_dn = softplus_f(p_lbd[0]);
    const float gamma = softplus_f(p_lg[0]);

    float xv[8], pg[8];
    float sx2 = 0.f, so2 = 0.f, sod = 0.f, se2 = 0.f;
#pragma unroll
    for (int c = 0; c < 2; ++c) {
        const int j0 = c * 256 + lane * 4;
        float4 xx = *reinterpret_cast<const float4*>(x + base + j0);
        float4 mm = *reinterpret_cast<const float4*>(ema_mean + j0);
        float4 qq = *reinterpret_cast<const float4*>(ema_sq + j0);
        float4 eo = *reinterpret_cast<const float4*>(ema_out + j0);
        float vv[4] = {xx.x, xx.y, xx.z, xx.w};
        float vm[4] = {mm.x, mm.y, mm.z, mm.w};
        float vq[4] = {qq.x, qq.y, qq.z, qq.w};
        float ve[4] = {eo.x, eo.y, eo.z, eo.w};
#pragma unroll
        for (int q = 0; q < 4; ++q) {
            const int e = c * 4 + q;
            float xf = vv[q];
            xv[e] = xf;
            float x3 = xf * xf * xf;
            float gl = 0.5f * xf * (1.0f + tanh_fast(0.7978845608028654f * (xf + 0.044715f * x3)));
            float var = fmaxf(vq[q] - vm[q] * vm[q], 1e-4f);
            float istd = __builtin_amdgcn_rcpf(sqrtf(var) + 1e-5f);
            float z = (xf - vm[q]) * istd;
            float th = tanh_fast(gamma * z);
            float up = beta_up * fmaxf(th, 0.0f);
            float dn = beta_dn * fmaxf(-th, 0.0f);
            float gh = fminf(fmaxf(1.0f + up - dn, 0.05f), 8.0f);
            pg[e] = gl * gh;
            sx2 += xf * xf;
            so2 += gl * gl;
            sod += gl * ve[q];
            se2 += ve[q] * ve[q];
        }
    }
#pragma unroll
    for (int off = 32; off; off >>= 1) {
        sx2 += __shfl_xor(sx2, off);
        so2 += __shfl_xor(so2, off);
        sod += __shfl_xor(sod, off);
        se2 += __shfl_xor(se2, off);
    }
    const float qscale = 127.0f * __builtin_amdgcn_rcpf(fmaxf(sqrtf(sx2), 1e-12f));
    const float inv_en = __builtin_amdgcn_rcpf(fmaxf(sqrtf(se2), 1e-12f));
    float cosv = sod * inv_en * __builtin_amdgcn_rcpf(fmaxf(sqrtf(so2), 1e-12f));
    cosv = fminf(fmaxf(cosv, -1.0f), 1.0f);
    const float gcos = exp_fast(-tau * cosv);

#pragma unroll
    for (int c = 0; c < 2; ++c) {
        const int j0 = c * 256 + lane * 4;
        ushort4 pb;
        pb.x = cvt_bf16(pg[c * 4 + 0] * gcos);
        pb.y = cvt_bf16(pg[c * 4 + 1] * gcos);
        pb.z = cvt_bf16(pg[c * 4 + 2] * gcos);
        pb.w = cvt_bf16(pg[c * 4 + 3] * gcos);
        *reinterpret_cast<ushort4*>(po + base + j0) = pb;
        int q0 = __float2int_rn(xv[c * 4 + 0] * qscale);
        int q1 = __float2int_rn(xv[c * 4 + 1] * qscale);
        int q2 = __float2int_rn(xv[c * 4 + 2] * qscale);
        int q3 = __float2int_rn(xv[c * 4 + 3] * qscale);
        int pk = (q0 & 255) | ((q1 & 255) << 8) | ((q2 & 255) << 16) | (q3 << 24);
        *reinterpret_cast<int*>(xn8 + base + j0) = pk;
    }
}

// ---------------- K2: symmetric sim row/col max, int8 MFMA, 128x128 tri-tiles ----
// 136 tiles/batch (tm<=tn), 1088 blocks of 256 thr = 4 waves (2x2), wave tile
// 64x64, acc 64 VGPR -> (256,4): FOUR independent blocks/CU (16 waves/CU) —
// finer grid granularity kills R12's 33% 3-round tail (576 blocks @ 2/CU), and
// cross-block TLP covers the 2-phase drains (m114/m230: 2ph ~= 92% of 8ph).
// LDS 2 slots x (A 8 KB | B 8 KB) = 32 KB; BK=64 i8 bytes; same R8-PMC-verified
// 0-conflict swizzle (2 logical 64B rows per 128B LDS row, byte^=((sup&7)<<4));
// gload_lds dest linear, global source inverse-swizzled (rule 21).
// Row-max -> partial[.][tn]; col-max (tm!=tn) -> partial[.][16+tm]. Diagonal
// tiles mask rl==cl. Epilogue scales by 1/127^2.
__global__ __launch_bounds__(256, 4) void k2_nn(const unsigned char* __restrict__ xn8,
                                                float* __restrict__ partial) {
    __shared__ char lds[32768];  // 2 slots x (A 8 KB | B 8 KB)

    const int tid = threadIdx.x;
    const int wave = tid >> 6;
    const int lane = tid & 63;
    const int r15 = lane & 15;
    const int kgrp = lane >> 4;
    const int wr = wave >> 1;  // 0..1 (row half)
    const int wc = wave & 1;   // 0..1 (col half)

    const int bid = blockIdx.x;
    const int b = bid & 7;  // XCD pin (1088 % 8 == 0 -> bijective)
    int t = bid >> 3;       // 0..135
    int tm = 0;
    while (t >= 16 - tm) { t -= 16 - tm; ++tm; }
    const int tn = tm + t;

    const size_t bbase = (size_t)b * TT * DD;
    const unsigned char* Ag = xn8 + bbase + (size_t)tm * 128 * DD;
    const unsigned char* Bg = xn8 + bbase + (size_t)tn * 128 * DD;

    i32x4 acc[4][4];
#pragma unroll
    for (int i = 0; i < 4; ++i)
#pragma unroll
        for (int j = 0; j < 4; ++j) acc[i][j] = (i32x4){0, 0, 0, 0};

    // stage one K-tile (64 i8 cols): A 2 + B 2 loads per thread
    auto stage = [&](int slot, int kt) {
#pragma unroll
        for (int l = 0; l < 2; ++l) {
            const int o = l * 4096 + tid * 16;
            const int sup = o >> 7;
            const int w = (o & 127) ^ ((sup & 7) << 4);
            const int row = sup * 2 + (w >> 6);
            const int cb = w & 63;
            load_lds16(Ag + (size_t)row * DD + kt * 64 + cb, lds + slot * 16384 + o);
            load_lds16(Bg + (size_t)row * DD + kt * 64 + cb, lds + slot * 16384 + 8192 + o);
        }
    };

#define LADDR(R) \
    (((R) >> 1) * 128 + (((((R) & 1) << 6) + (kgrp << 4)) ^ ((((R) >> 1) & 7) << 4)))

    auto compute = [&](int slot) {
        const char* sA = lds + slot * 16384;
        const char* sB = sA + 8192;
        i32x4 av[4], bv[4];
#pragma unroll
        for (int ni = 0; ni < 4; ++ni)
            bv[ni] = *(const i32x4*)(sB + LADDR(wc * 64 + ni * 16 + r15));
#pragma unroll
        for (int mi = 0; mi < 4; ++mi)
            av[mi] = *(const i32x4*)(sA + LADDR(wr * 64 + mi * 16 + r15));
        __builtin_amdgcn_s_setprio(1);
#pragma unroll
        for (int mi = 0; mi < 4; ++mi)
#pragma unroll
            for (int ni = 0; ni < 4; ++ni)
                acc[mi][ni] = __builtin_amdgcn_mfma_i32_16x16x64_i8(av[mi], bv[ni],
                                                                    acc[mi][ni], 0, 0, 0);
        __builtin_amdgcn_s_setprio(0);
    };
#undef LADDR

    // proven R5-style 2-phase: stage(next) issued before compute(cur);
    // one __syncthreads (vmcnt0+lgkm0+barrier) per K-tile.
    stage(0, 0);
    __syncthreads();
#pragma unroll
    for (int kt = 0; kt < 8; ++kt) {
        if (kt < 7) stage((kt + 1) & 1, kt + 1);
        compute(kt & 1);
        if (kt < 7) __syncthreads();
    }

    // ---- epilogue ----
    // D layout: col cl = wc*64 + ni*16 + r15, row rl = wr*64 + mi*16 + kgrp*4 + rr
    const float inv_qq = 1.0f / (127.0f * 127.0f);
    const bool diag = (tm == tn);
    float accf[4][4][4];
#pragma unroll
    for (int mi = 0; mi < 4; ++mi)
#pragma unroll
        for (int ni = 0; ni < 4; ++ni)
#pragma unroll
            for (int rr = 0; rr < 4; ++rr) {
                float e = (float)acc[mi][ni][rr] * inv_qq;
                if (diag) {
                    const int rl = wr * 64 + mi * 16 + kgrp * 4 + rr;
                    const int cl = wc * 64 + ni * 16 + r15;
                    if (rl == cl) e = -2.0f;
                }
                accf[mi][ni][rr] = e;
            }
    // row-max: fold ni, shfl over the 16 col-lanes
    float rmx[4][4];
#pragma unroll
    for (int mi = 0; mi < 4; ++mi)
#pragma unroll
        for (int rr = 0; rr < 4; ++rr) {
            float v = fmaxf(fmaxf(accf[mi][0][rr], accf[mi][1][rr]),
                            fmaxf(accf[mi][2][rr], accf[mi][3][rr]));
            v = fmaxf(v, __shfl_xor(v, 1));
            v = fmaxf(v, __shfl_xor(v, 2));
            v = fmaxf(v, __shfl_xor(v, 4));
            v = fmaxf(v, __shfl_xor(v, 8));
            rmx[mi][rr] = v;
        }
    // col-max: fold mi,rr in-lane, shfl across kgrp
    float cmx[4];
#pragma unroll
    for (int ni = 0; ni < 4; ++ni) {
        float v = -2.0f;
#pragma unroll
        for (int mi = 0; mi < 4; ++mi)
#pragma unroll
            for (int rr = 0; rr < 4; ++rr) v = fmaxf(v, accf[mi][ni][rr]);
        v = fmaxf(v, __shfl_xor(v, 16));
        v = fmaxf(v, __shfl_xor(v, 32));
        cmx[ni] = v;
    }
    __syncthreads();  // all LDS tile reads + stages done; alias reduce bufs
    float* rbuf = (float*)lds;           // [128][2] (wc)
    float* cbuf = (float*)(lds + 1024);  // [128][2] (wr)
    if (r15 == 0) {
#pragma unroll
        for (int mi = 0; mi < 4; ++mi)
#pragma unroll
            for (int rr = 0; rr < 4; ++rr)
                rbuf[(wr * 64 + mi * 16 + kgrp * 4 + rr) * 2 + wc] = rmx[mi][rr];
    }
    if (kgrp == 0) {
#pragma unroll
        for (int ni = 0; ni < 4; ++ni)
            cbuf[(wc * 64 + ni * 16 + r15) * 2 + wr] = cmx[ni];
    }
    __syncthreads();
    if (tid < 128) {
        const float v = fmaxf(rbuf[tid * 2 + 0], rbuf[tid * 2 + 1]);
        partial[((size_t)b * TT + tm * 128 + tid) * NSL + tn] = v;
    } else if (!diag) {
        const int c = tid - 128;
        const float v = fmaxf(cbuf[c * 2 + 0], cbuf[c * 2 + 1]);
        partial[((size_t)b * TT + tn * 128 + c) * NSL + 16 + tm] = v;
    }
}

// ---------------- K3: reduce partial maxes + gate_nn scale + final write ----------------
// 256 threads = 4 waves; one wave per row; reads bf16 PO, writes f32 out.
// Row in 128-panel p: valid slots = {tn : tn >= p} U {16+tm : tm < p}.
__global__ __launch_bounds__(256) void k3_scale(float* __restrict__ out,
                                                const unsigned short* __restrict__ po,
                                                const float* __restrict__ partial,
                                                const float* __restrict__ p_lsn,
                                                const float* __restrict__ p_lwn) {
    const int row = blockIdx.x * 4 + (threadIdx.x >> 6);
    const int lane = threadIdx.x & 63;
    const float sigma_nn = softplus_f(p_lsn[0]);
    const float w_nn = softplus_f(p_lwn[0]);

    const int p = (row & (TT - 1)) >> 7;  // 128-row panel of this row
    float v = -2.0f;
    if (lane < 16) {
        if (lane >= p) v = partial[(size_t)row * NSL + lane];
    } else if (lane < NSL) {
        if (lane - 16 < p) v = partial[(size_t)row * NSL + lane];
    }
    v = fmaxf(v, __shfl_xor(v, 1));
    v = fmaxf(v, __shfl_xor(v, 2));
    v = fmaxf(v, __shfl_xor(v, 4));
    v = fmaxf(v, __shfl_xor(v, 8));
    v = fmaxf(v, __shfl_xor(v, 16));
    v = fmaxf(v, __shfl_xor(v, 32));
    const float g = 1.0f + w_nn * tanh_fast(sigma_nn * 0.5f * (1.0f - v));

    const size_t base = (size_t)row * DD + lane * 8;
    ushort4 p0 = *reinterpret_cast<const ushort4*>(po + base);
    ushort4 p1 = *reinterpret_cast<const ushort4*>(po + base + 4);
    float4 o0, o1;
    o0.x = bf2f(p0.x) * g; o0.y = bf2f(p0.y) * g;
    o0.z = bf2f(p0.z) * g; o0.w = bf2f(p0.w) * g;
    o1.x = bf2f(p1.x) * g; o1.y = bf2f(p1.y) * g;
    o1.z = bf2f(p1.z) * g; o1.w = bf2f(p1.w) * g;
    *reinterpret_cast<float4*>(out + base) = o0;
    *reinterpret_cast<float4*>(out + base + 4) = o1;
}

extern "C" void kernel_launch(void* const* d_in, const int* in_sizes, int n_in,
                              void* d_out, int out_size, void* d_ws, size_t ws_size,
                              hipStream_t stream) {
    const float* x = (const float*)d_in[0];
    const float* ema_mean = (const float*)d_in[1];
    const float* ema_sq = (const float*)d_in[2];
    const float* ema_out = (const float*)d_in[3];
    const float* log_tau = (const float*)d_in[4];
    const float* log_beta_up = (const float*)d_in[5];
    const float* log_beta_dn = (const float*)d_in[6];
    const float* log_gamma = (const float*)d_in[7];
    const float* log_sigma_nn = (const float*)d_in[8];
    const float* log_w_nn = (const float*)d_in[9];

    // ws layout: XN8 i8 [B*T*D] (8.39 MB) | PO bf16 [B*T*D] (16.78 MB)
    //            | partial f32[B*T][NSL] (2.1 MB)
    char* ws = (char*)d_ws;
    unsigned char* XN8 = (unsigned char*)ws;
    unsigned short* PO = (unsigned short*)(ws + 8388608);
    float* partial = (float*)(ws + 8388608 + 16777216);
    float* out = (float*)d_out;

    hipLaunchKernelGGL(k1_elem, dim3(BB * TT / 4), dim3(256), 0, stream, x, ema_mean, ema_sq,
                       ema_out, log_tau, log_beta_up, log_beta_dn, log_gamma, XN8, PO);
    hipLaunchKernelGGL(k2_nn, dim3(BB * 136), dim3(256), 0, stream, XN8, partial);
    hipLaunchKernelGGL(k3_scale, dim3(BB * TT / 4), dim3(256), 0, stream, out, PO, partial,
                       log_sigma_nn, log_w_nn);
}

// Round 14
// 60.009 us; speedup vs baseline: 1.3034x; 1.0119x over previous
//
#include <hip/hip_runtime.h>
#include <hip/hip_bf16.h>
#include <math.h>

#define BB 8
#define TT 2048
#define DD 512
#define NSL 32  // slots: 0..15 row-max by tn; 16..31 col-max by tm (tm<p valid)

typedef __attribute__((ext_vector_type(8))) short bf16x8;
typedef __attribute__((ext_vector_type(4))) float f32x4;
typedef __attribute__((ext_vector_type(4))) int i32x4;

__device__ inline float softplus_f(float v) { return log1pf(expf(v)); }

// fast tanh: 1 - 2/(exp2(2*log2e*y)+1); v_exp_f32 + v_rcp_f32, ~1e-6 rel err
__device__ inline float tanh_fast(float y) {
    float e = __builtin_amdgcn_exp2f(y * 2.8853900817779268f);
    return 1.0f - 2.0f * __builtin_amdgcn_rcpf(e + 1.0f);
}
__device__ inline float exp_fast(float y) {
    return __builtin_amdgcn_exp2f(y * 1.4426950408889634f);
}

// f32 -> bf16 via compiler cast (emits v_cvt_pk_bf16_f32 pairs; m240)
__device__ inline unsigned short cvt_bf16(float f) {
    __hip_bfloat16 h = (__hip_bfloat16)f;
    return *reinterpret_cast<unsigned short*>(&h);
}
__device__ inline float bf2f(unsigned short h) {
    unsigned int u = ((unsigned int)h) << 16;
    return __uint_as_float(u);
}

__device__ inline void load_lds16(const void* g, void* l) {
    __builtin_amdgcn_global_load_lds(
        (const __attribute__((address_space(1))) unsigned int*)g,
        (__attribute__((address_space(3))) unsigned int*)l, 16, 0, 0);
}

// ---------------- K1: fused prep + per-row elementwise + reductions ----------------
// 256 threads = 4 waves; one wave per row of D=512; 8 elems/thread.
// All 8 global float4 loads issued before the compute chain (ILP).
__global__ __launch_bounds__(256) void k1_elem(
    const float* __restrict__ x, const float* __restrict__ ema_mean,
    const float* __restrict__ ema_sq, const float* __restrict__ ema_out,
    const float* __restrict__ p_log_tau, const float* __restrict__ p_lbu,
    const float* __restrict__ p_lbd, const float* __restrict__ p_lg,
    unsigned char* __restrict__ xn8, unsigned short* __restrict__ po) {
    const int row = blockIdx.x * 4 + (threadIdx.x >> 6);
    const int lane = threadIdx.x & 63;
    const size_t base = (size_t)row * DD;
    const int j0 = lane * 4, j1 = 256 + lane * 4;

    // issue all loads first
    float4 xx0 = *reinterpret_cast<const float4*>(x + base + j0);
    float4 xx1 = *reinterpret_cast<const float4*>(x + base + j1);
    float4 mm0 = *reinterpret_cast<const float4*>(ema_mean + j0);
    float4 mm1 = *reinterpret_cast<const float4*>(ema_mean + j1);
    float4 qq0 = *reinterpret_cast<const float4*>(ema_sq + j0);
    float4 qq1 = *reinterpret_cast<const float4*>(ema_sq + j1);
    float4 eo0 = *reinterpret_cast<const float4*>(ema_out + j0);
    float4 eo1 = *reinterpret_cast<const float4*>(ema_out + j1);

    const float tau = expf(p_log_tau[0]);
    const float beta_up = softplus_f(p_lbu[0]);
    const float beta_dn = softplus_f(p_lbd[0]);
    const float gamma = softplus_f(p_lg[0]);

    float xv[8], pg[8];
    float sx2 = 0.f, so2 = 0.f, sod = 0.f, se2 = 0.f;
    float vv[8] = {xx0.x, xx0.y, xx0.z, xx0.w, xx1.x, xx1.y, xx1.z, xx1.w};
    float vm[8] = {mm0.x, mm0.y, mm0.z, mm0.w, mm1.x, mm1.y, mm1.z, mm1.w};
    float vq[8] = {qq0.x, qq0.y, qq0.z, qq0.w, qq1.x, qq1.y, qq1.z, qq1.w};
    float ve[8] = {eo0.x, eo0.y, eo0.z, eo0.w, eo1.x, eo1.y, eo1.z, eo1.w};
#pragma unroll
    for (int e = 0; e < 8; ++e) {
        float xf = vv[e];
        xv[e] = xf;
        float x3 = xf * xf * xf;
        float gl = 0.5f * xf * (1.0f + tanh_fast(0.7978845608028654f * (xf + 0.044715f * x3)));
        float var = fmaxf(vq[e] - vm[e] * vm[e], 1e-4f);
        float istd = __builtin_amdgcn_rcpf(sqrtf(var) + 1e-5f);
        float z = (xf - vm[e]) * istd;
        float th = tanh_fast(gamma * z);
        float up = beta_up * fmaxf(th, 0.0f);
        float dn = beta_dn * fmaxf(-th, 0.0f);
        float gh = fminf(fmaxf(1.0f + up - dn, 0.05f), 8.0f);
        pg[e] = gl * gh;
        sx2 += xf * xf;
        so2 += gl * gl;
        sod += gl * ve[e];
        se2 += ve[e] * ve[e];
    }
#pragma unroll
    for (int off = 32; off; off >>= 1) {
        sx2 += __shfl_xor(sx2, off);
        so2 += __shfl_xor(so2, off);
        sod += __shfl_xor(sod, off);
        se2 += __shfl_xor(se2, off);
    }
    const float qscale = 127.0f * __builtin_amdgcn_rcpf(fmaxf(sqrtf(sx2), 1e-12f));
    const float inv_en = __builtin_amdgcn_rcpf(fmaxf(sqrtf(se2), 1e-12f));
    float cosv = sod * inv_en * __builtin_amdgcn_rcpf(fmaxf(sqrtf(so2), 1e-12f));
    cosv = fminf(fmaxf(cosv, -1.0f), 1.0f);
    const float gcos = exp_fast(-tau * cosv);

#pragma unroll
    for (int c = 0; c < 2; ++c) {
        const int j = c * 256 + lane * 4;
        ushort4 pb;
        pb.x = cvt_bf16(pg[c * 4 + 0] * gcos);
        pb.y = cvt_bf16(pg[c * 4 + 1] * gcos);
        pb.z = cvt_bf16(pg[c * 4 + 2] * gcos);
        pb.w = cvt_bf16(pg[c * 4 + 3] * gcos);
        *reinterpret_cast<ushort4*>(po + base + j) = pb;
        int q0 = __float2int_rn(xv[c * 4 + 0] * qscale);
        int q1 = __float2int_rn(xv[c * 4 + 1] * qscale);
        int q2 = __float2int_rn(xv[c * 4 + 2] * qscale);
        int q3 = __float2int_rn(xv[c * 4 + 3] * qscale);
        int pk = (q0 & 255) | ((q1 & 255) << 8) | ((q2 & 255) << 16) | (q3 << 24);
        *reinterpret_cast<int*>(xn8 + base + j) = pk;
    }
}

// ---------------- K2: symmetric sim row/col max, int8 MFMA, 128x128 tri-tiles ----
// R13 geometry (1088 blocks, 4 waves, 64x64/wave, balanced) + R12 envelope
// (3 LDS slots, counted vmcnt(4) at boundaries, raw s_barrier — loads stay in
// flight across barriers, T4). LDS 3 x 16 KB = 48 KB -> 3 blocks/CU (12
// waves/CU TLP). Same R8-PMC-verified 0-conflict swizzle; gload_lds dest
// linear, global source inverse-swizzled (rule 21). Epilogue scales 1/127^2.
__global__ __launch_bounds__(256, 3) void k2_nn(const unsigned char* __restrict__ xn8,
                                                float* __restrict__ partial) {
    __shared__ char lds[49152];  // 3 slots x (A 8 KB | B 8 KB)

    const int tid = threadIdx.x;
    const int wave = tid >> 6;
    const int lane = tid & 63;
    const int r15 = lane & 15;
    const int kgrp = lane >> 4;
    const int wr = wave >> 1;  // 0..1 (row half)
    const int wc = wave & 1;   // 0..1 (col half)

    const int bid = blockIdx.x;
    const int b = bid & 7;  // XCD pin (1088 % 8 == 0 -> bijective)
    int t = bid >> 3;       // 0..135
    int tm = 0;
    while (t >= 16 - tm) { t -= 16 - tm; ++tm; }
    const int tn = tm + t;

    const size_t bbase = (size_t)b * TT * DD;
    const unsigned char* Ag = xn8 + bbase + (size_t)tm * 128 * DD;
    const unsigned char* Bg = xn8 + bbase + (size_t)tn * 128 * DD;

    i32x4 acc[4][4];
#pragma unroll
    for (int i = 0; i < 4; ++i)
#pragma unroll
        for (int j = 0; j < 4; ++j) acc[i][j] = (i32x4){0, 0, 0, 0};

    // stage one K-tile (64 i8 cols): A 2 + B 2 loads per thread
    auto stage = [&](int slot, int kt) {
#pragma unroll
        for (int l = 0; l < 2; ++l) {
            const int o = l * 4096 + tid * 16;
            const int sup = o >> 7;
            const int w = (o & 127) ^ ((sup & 7) << 4);
            const int row = sup * 2 + (w >> 6);
            const int cb = w & 63;
            load_lds16(Ag + (size_t)row * DD + kt * 64 + cb, lds + slot * 16384 + o);
            load_lds16(Bg + (size_t)row * DD + kt * 64 + cb, lds + slot * 16384 + 8192 + o);
        }
    };

#define LADDR(R) \
    (((R) >> 1) * 128 + (((((R) & 1) << 6) + (kgrp << 4)) ^ ((((R) >> 1) & 7) << 4)))

    auto compute = [&](int slot) {
        const char* sA = lds + slot * 16384;
        const char* sB = sA + 8192;
        i32x4 av[4], bv[4];
#pragma unroll
        for (int ni = 0; ni < 4; ++ni)
            bv[ni] = *(const i32x4*)(sB + LADDR(wc * 64 + ni * 16 + r15));
#pragma unroll
        for (int mi = 0; mi < 4; ++mi)
            av[mi] = *(const i32x4*)(sA + LADDR(wr * 64 + mi * 16 + r15));
        __builtin_amdgcn_s_setprio(1);
#pragma unroll
        for (int mi = 0; mi < 4; ++mi)
#pragma unroll
            for (int ni = 0; ni < 4; ++ni)
                acc[mi][ni] = __builtin_amdgcn_mfma_i32_16x16x64_i8(av[mi], bv[ni],
                                                                    acc[mi][ni], 0, 0, 0);
        __builtin_amdgcn_s_setprio(0);
    };
#undef LADDR

    // prologue: stage tiles 0,1 (8 loads); vmcnt(4) -> tile 0 landed, tile 1 in flight
    stage(0, 0);
    stage(1, 1);
    asm volatile("s_waitcnt vmcnt(4)" ::: "memory");
    __builtin_amdgcn_s_barrier();
    __builtin_amdgcn_sched_barrier(0);

#pragma unroll
    for (int kt = 0; kt < 8; ++kt) {
        if (kt + 2 < 8) stage((kt + 2) % 3, kt + 2);  // slot of tile kt-1: reads done last iter
        compute(kt % 3);
        if (kt < 7) {
            if (kt + 2 < 8)
                asm volatile("s_waitcnt vmcnt(4)" ::: "memory");  // tile kt+1 landed
            else
                asm volatile("s_waitcnt vmcnt(0)" ::: "memory");  // tail drain
            __builtin_amdgcn_s_barrier();
            __builtin_amdgcn_sched_barrier(0);
        }
    }

    // ---- epilogue ----
    // D layout: col cl = wc*64 + ni*16 + r15, row rl = wr*64 + mi*16 + kgrp*4 + rr
    const float inv_qq = 1.0f / (127.0f * 127.0f);
    const bool diag = (tm == tn);
    float accf[4][4][4];
#pragma unroll
    for (int mi = 0; mi < 4; ++mi)
#pragma unroll
        for (int ni = 0; ni < 4; ++ni)
#pragma unroll
            for (int rr = 0; rr < 4; ++rr) {
                float e = (float)acc[mi][ni][rr] * inv_qq;
                if (diag) {
                    const int rl = wr * 64 + mi * 16 + kgrp * 4 + rr;
                    const int cl = wc * 64 + ni * 16 + r15;
                    if (rl == cl) e = -2.0f;
                }
                accf[mi][ni][rr] = e;
            }
    // row-max: fold ni, shfl over the 16 col-lanes
    float rmx[4][4];
#pragma unroll
    for (int mi = 0; mi < 4; ++mi)
#pragma unroll
        for (int rr = 0; rr < 4; ++rr) {
            float v = fmaxf(fmaxf(accf[mi][0][rr], accf[mi][1][rr]),
                            fmaxf(accf[mi][2][rr], accf[mi][3][rr]));
            v = fmaxf(v, __shfl_xor(v, 1));
            v = fmaxf(v, __shfl_xor(v, 2));
            v = fmaxf(v, __shfl_xor(v, 4));
            v = fmaxf(v, __shfl_xor(v, 8));
            rmx[mi][rr] = v;
        }
    // col-max: fold mi,rr in-lane, shfl across kgrp
    float cmx[4];
#pragma unroll
    for (int ni = 0; ni < 4; ++ni) {
        float v = -2.0f;
#pragma unroll
        for (int mi = 0; mi < 4; ++mi)
#pragma unroll
            for (int rr = 0; rr < 4; ++rr) v = fmaxf(v, accf[mi][ni][rr]);
        v = fmaxf(v, __shfl_xor(v, 16));
        v = fmaxf(v, __shfl_xor(v, 32));
        cmx[ni] = v;
    }
    __syncthreads();  // all LDS tile reads + stages done; alias reduce bufs
    float* rbuf = (float*)lds;           // [128][2] (wc)
    float* cbuf = (float*)(lds + 1024);  // [128][2] (wr)
    if (r15 == 0) {
#pragma unroll
        for (int mi = 0; mi < 4; ++mi)
#pragma unroll
            for (int rr = 0; rr < 4; ++rr)
                rbuf[(wr * 64 + mi * 16 + kgrp * 4 + rr) * 2 + wc] = rmx[mi][rr];
    }
    if (kgrp == 0) {
#pragma unroll
        for (int ni = 0; ni < 4; ++ni)
            cbuf[(wc * 64 + ni * 16 + r15) * 2 + wr] = cmx[ni];
    }
    __syncthreads();
    if (tid < 128) {
        const float v = fmaxf(rbuf[tid * 2 + 0], rbuf[tid * 2 + 1]);
        partial[((size_t)b * TT + tm * 128 + tid) * NSL + tn] = v;
    } else if (!diag) {
        const int c = tid - 128;
        const float v = fmaxf(cbuf[c * 2 + 0], cbuf[c * 2 + 1]);
        partial[((size_t)b * TT + tn * 128 + c) * NSL + 16 + tm] = v;
    }
}

// ---------------- K3: reduce partial maxes + gate_nn scale + final write ----------------
// 256 threads = 4 waves; one wave per row; reads bf16 PO, writes f32 out.
// Row in 128-panel p: valid slots = {tn : tn >= p} U {16+tm : tm < p}.
__global__ __launch_bounds__(256) void k3_scale(float* __restrict__ out,
                                                const unsigned short* __restrict__ po,
                                                const float* __restrict__ partial,
                                                const float* __restrict__ p_lsn,
                                                const float* __restrict__ p_lwn) {
    const int row = blockIdx.x * 4 + (threadIdx.x >> 6);
    const int lane = threadIdx.x & 63;
    const float sigma_nn = softplus_f(p_lsn[0]);
    const float w_nn = softplus_f(p_lwn[0]);

    const int p = (row & (TT - 1)) >> 7;  // 128-row panel of this row
    float v = -2.0f;
    if (lane < 16) {
        if (lane >= p) v = partial[(size_t)row * NSL + lane];
    } else if (lane < NSL) {
        if (lane - 16 < p) v = partial[(size_t)row * NSL + lane];
    }
    v = fmaxf(v, __shfl_xor(v, 1));
    v = fmaxf(v, __shfl_xor(v, 2));
    v = fmaxf(v, __shfl_xor(v, 4));
    v = fmaxf(v, __shfl_xor(v, 8));
    v = fmaxf(v, __shfl_xor(v, 16));
    v = fmaxf(v, __shfl_xor(v, 32));
    const float g = 1.0f + w_nn * tanh_fast(sigma_nn * 0.5f * (1.0f - v));

    const size_t base = (size_t)row * DD + lane * 8;
    ushort4 p0 = *reinterpret_cast<const ushort4*>(po + base);
    ushort4 p1 = *reinterpret_cast<const ushort4*>(po + base + 4);
    float4 o0, o1;
    o0.x = bf2f(p0.x) * g; o0.y = bf2f(p0.y) * g;
    o0.z = bf2f(p0.z) * g; o0.w = bf2f(p0.w) * g;
    o1.x = bf2f(p1.x) * g; o1.y = bf2f(p1.y) * g;
    o1.z = bf2f(p1.z) * g; o1.w = bf2f(p1.w) * g;
    *reinterpret_cast<float4*>(out + base) = o0;
    *reinterpret_cast<float4*>(out + base + 4) = o1;
}

extern "C" void kernel_launch(void* const* d_in, const int* in_sizes, int n_in,
                              void* d_out, int out_size, void* d_ws, size_t ws_size,
                              hipStream_t stream) {
    const float* x = (const float*)d_in[0];
    const float* ema_mean = (const float*)d_in[1];
    const float* ema_sq = (const float*)d_in[2];
    const float* ema_out = (const float*)d_in[3];
    const float* log_tau = (const float*)d_in[4];
    const float* log_beta_up = (const float*)d_in[5];
    const float* log_beta_dn = (const float*)d_in[6];
    const float* log_gamma = (const float*)d_in[7];
    const float* log_sigma_nn = (const float*)d_in[8];
    const float* log_w_nn = (const float*)d_in[9];

    // ws layout: XN8 i8 [B*T*D] (8.39 MB) | PO bf16 [B*T*D] (16.78 MB)
    //            | partial f32[B*T][NSL] (2.1 MB)
    char* ws = (char*)d_ws;
    unsigned char* XN8 = (unsigned char*)ws;
    unsigned short* PO = (unsigned short*)(ws + 8388608);
    float* partial = (float*)(ws + 8388608 + 16777216);
    float* out = (float*)d_out;

    hipLaunchKernelGGL(k1_elem, dim3(BB * TT / 4), dim3(256), 0, stream, x, ema_mean, ema_sq,
                       ema_out, log_tau, log_beta_up, log_beta_dn, log_gamma, XN8, PO);
    hipLaunchKernelGGL(k2_nn, dim3(BB * 136), dim3(256), 0, stream, XN8, partial);
    hipLaunchKernelGGL(k3_scale, dim3(BB * TT / 4), dim3(256), 0, stream, out, PO, partial,
                       log_sigma_nn, log_w_nn);
}